// Round 9
// baseline (612.241 us; speedup 1.0000x reference)
//
#include <hip/hip_runtime.h>
#include <math.h>

#define NN 20000
#define NE 200000
#define HH 512

typedef __attribute__((ext_vector_type(8))) short short8v;
typedef __attribute__((ext_vector_type(4))) float f32x4;

__device__ inline short f2bf(float f) {
    union { float f; unsigned u; } v; v.f = f;
    unsigned r = (v.u + 0x7fffu + ((v.u >> 16) & 1u)) >> 16;
    return (short)r;
}
__device__ inline float bf2f(short s) {
    union { unsigned u; float f; } v;
    v.u = ((unsigned)(unsigned short)s) << 16;
    return v.f;
}

// direct global->LDS DMA, 16B per lane; lds dest must be wave-uniform base
__device__ inline void gload_lds16(const void* g, void* l) {
    __builtin_amdgcn_global_load_lds(
        (const __attribute__((address_space(1))) void*)g,
        (__attribute__((address_space(3))) void*)l, 16, 0, 0);
}

// ---------------- fp32 -> bf16 bulk convert (8 elems/thread) ----------------
__global__ __launch_bounds__(256)
void f2b_kernel(const float* __restrict__ src, short* __restrict__ dst, int n8)
{
    int i = blockIdx.x * 256 + threadIdx.x;
    if (i >= n8) return;
    const float4* p = (const float4*)src + (size_t)i * 2;
    float4 a = p[0], b = p[1];
    short8v s;
    s[0] = f2bf(a.x); s[1] = f2bf(a.y); s[2] = f2bf(a.z); s[3] = f2bf(a.w);
    s[4] = f2bf(b.x); s[5] = f2bf(b.y); s[6] = f2bf(b.z); s[7] = f2bf(b.w);
    ((short8v*)dst)[i] = s;
}

// ---------------- weight transpose + bf16 convert: dst[n][k] = src[k][n] ----
__global__ __launch_bounds__(256)
void wtr_kernel(const float* __restrict__ src, short* __restrict__ dst,
                int K, int Ncols)
{
    __shared__ float t[32][33];
    int bx = blockIdx.x * 32;
    int by = blockIdx.y * 32;
    int tx = threadIdx.x, ty = threadIdx.y;
    for (int i = ty; i < 32; i += 8)
        t[i][tx] = src[(size_t)(by + i) * Ncols + bx + tx];
    __syncthreads();
    for (int i = ty; i < 32; i += 8)
        dst[(size_t)(bx + i) * K + by + tx] = f2bf(t[tx][i]);
}

// ---------------- MFMA GEMM: out[M,512] = X[M,K](bf16) @ WT[512,K](bf16)^T + b
// 128x64 tile, BK=32, 4 waves (4x1 rows; each wave 32 rows x 64 cols).
// 3-deep global_load_lds pipeline, counted vmcnt (6/3/0), 36 KB LDS.
__global__ __launch_bounds__(256)
void mfma_lin(const short* __restrict__ X, const short* __restrict__ WT,
              const float* __restrict__ bias, float* __restrict__ outF,
              short* __restrict__ outB, int M, int K)
{
    // per stage: A = slots [0,512) (128 rows x 4 chunks), B = [512,768) (64 x 4)
    __shared__ short8v pool[2304];   // 3 stages x 768 slots = 36 KB

    const int tid = threadIdx.x;
    const int lane = tid & 63;
    const int w = tid >> 6;

    const int nby = (M + 127) >> 7;
    const int nwg = nby << 3;                 // 8 col-blocks of 64
    const int q = nwg >> 3, r = nwg & 7;
    int id = blockIdx.x;
    int xcd = id & 7, wi = id >> 3;
    int wgid = (xcd < r ? xcd * (q + 1) : r * (q + 1) + (xcd - r) * q) + wi;
    const int col0 = (wgid & 7) * 64;
    const int row0 = (wgid >> 3) * 128;

    // staging: 768 slots/stage, 3 per thread (wave w covers [w*192, w*192+192))
    const short* gsrc[3];
#pragma unroll
    for (int g = 0; g < 3; ++g) {
        int p = w * 192 + g * 64 + lane;
        if (p < 512) {
            int row = p >> 2;
            int c = (p & 3) ^ ((row >> 1) & 3);
            int ga = row0 + row; if (ga >= M) ga = M - 1;
            gsrc[g] = X + (size_t)ga * K + c * 8;
        } else {
            int qq = p - 512;
            int col = qq >> 2;
            int c = (qq & 3) ^ ((col >> 1) & 3);
            gsrc[g] = WT + (size_t)(col0 + col) * K + c * 8;
        }
    }

    // fragment read indices (chunk-XOR swizzle)
    int ar[2], br[4];
#pragma unroll
    for (int i = 0; i < 2; ++i) {
        int rr = w * 32 + i * 16 + (lane & 15);
        ar[i] = rr * 4 + ((lane >> 4) ^ ((rr >> 1) & 3));
    }
#pragma unroll
    for (int j = 0; j < 4; ++j) {
        int nn = j * 16 + (lane & 15);
        br[j] = 512 + nn * 4 + ((lane >> 4) ^ ((nn >> 1) & 3));
    }

    f32x4 acc[2][4];
#pragma unroll
    for (int i = 0; i < 2; ++i)
#pragma unroll
        for (int j = 0; j < 4; ++j)
            acc[i][j] = (f32x4){0.f, 0.f, 0.f, 0.f};

    auto stage = [&](int buf, int kk) {
        short8v* base = pool + buf * 768 + w * 192;
#pragma unroll
        for (int g = 0; g < 3; ++g)
            gload_lds16(gsrc[g] + kk, base + g * 64);
    };

    const int nt = K >> 5;            // 8 or 16
    stage(0, 0);
    if (nt > 1) stage(1, 32);
    if (nt > 2) stage(2, 64);
    int cur = 0;
    for (int t = 0; t < nt; ++t) {
        // wait for stage t only (3 loads/thread/stage); keep younger in flight
        if (t + 2 < nt)      asm volatile("s_waitcnt vmcnt(6)" ::: "memory");
        else if (t + 1 < nt) asm volatile("s_waitcnt vmcnt(3)" ::: "memory");
        else                 asm volatile("s_waitcnt vmcnt(0)" ::: "memory");
        __builtin_amdgcn_s_barrier();
        const short8v* S = pool + cur * 768;
        short8v af[2], bf[4];
#pragma unroll
        for (int i = 0; i < 2; ++i) af[i] = S[ar[i]];
#pragma unroll
        for (int j = 0; j < 4; ++j) bf[j] = S[br[j]];
#pragma unroll
        for (int i = 0; i < 2; ++i)
#pragma unroll
            for (int j = 0; j < 4; ++j)
                acc[i][j] = __builtin_amdgcn_mfma_f32_16x16x32_bf16(af[i], bf[j], acc[i][j], 0, 0, 0);
        __builtin_amdgcn_s_barrier();          // all waves done reading buf cur
        if (t + 3 < nt) stage(cur, (t + 3) * 32);
        cur = (cur == 2) ? 0 : cur + 1;
    }

    float bj[4];
#pragma unroll
    for (int j = 0; j < 4; ++j)
        bj[j] = bias[col0 + j * 16 + (lane & 15)];

    if (outF) {   // fp32 path (prep residual only)
#pragma unroll
        for (int i = 0; i < 2; ++i) {
#pragma unroll
            for (int rr = 0; rr < 4; ++rr) {
                int row = row0 + w * 32 + i * 16 + (lane >> 4) * 4 + rr;
                if (row < M) {
                    float* op = outF + (size_t)row * HH + col0 + (lane & 15);
#pragma unroll
                    for (int j = 0; j < 4; ++j) op[j * 16] = acc[i][j][rr] + bj[j];
                }
            }
        }
    }
    if (outB) {   // bf16: wave-private LDS transpose -> coalesced short8 rows
        short* lds = (short*)pool + w * 2304;   // 32 rows x 72 shorts per wave
#pragma unroll
        for (int i = 0; i < 2; ++i)
#pragma unroll
            for (int rr = 0; rr < 4; ++rr) {
                int lrow = i * 16 + (lane >> 4) * 4 + rr;
#pragma unroll
                for (int j = 0; j < 4; ++j)
                    lds[lrow * 72 + j * 16 + (lane & 15)] = f2bf(acc[i][j][rr] + bj[j]);
            }
#pragma unroll
        for (int k = 0; k < 4; ++k) {
            int lr = (lane >> 3) + 8 * k;
            int lc = (lane & 7) * 8;
            int grow = row0 + w * 32 + lr;
            if (grow < M) {
                short8v vv = *(short8v*)(lds + lr * 72 + lc);
                *(short8v*)(outB + (size_t)grow * HH + col0 + lc) = vv;
            }
        }
    }
}

// ---------------- gat_pre: u = fW @ aw[:512], v = fW @ aw[512:], fb dots -----
__global__ __launch_bounds__(256)
void gat_pre_kernel(const float* __restrict__ fW, const float* __restrict__ fb,
                    const float* __restrict__ aw, float* __restrict__ uv,
                    float* __restrict__ s0t0)
{
    int row = blockIdx.x * 4 + (threadIdx.x >> 6);
    int lane = threadIdx.x & 63;
    const float4* ah = (const float4*)aw;
    const float4* at = (const float4*)(aw + HH);
    const float4* fp;
    if (row < 512)      fp = (const float4*)(fW + (size_t)row * HH);
    else if (row == 512) fp = (const float4*)fb;
    else return;
    float du = 0.f, dv = 0.f;
#pragma unroll
    for (int l = 0; l < 2; ++l) {
        int idx = lane * 2 + l;
        float4 f = fp[idx], a = ah[idx], b = at[idx];
        du += f.x*a.x + f.y*a.y + f.z*a.z + f.w*a.w;
        dv += f.x*b.x + f.y*b.y + f.z*b.z + f.w*b.w;
    }
#pragma unroll
    for (int m = 32; m >= 1; m >>= 1) {
        du += __shfl_xor(du, m);
        dv += __shfl_xor(dv, m);
    }
    if (lane == 0) {
        if (row < 512) { uv[row] = du; uv[512 + row] = dv; }
        else           { s0t0[0] = du; s0t0[1] = dv; }
    }
}

// ---------------- rowdot2: ss[n]=Head[n].u+s0, ts[n]=Tail[n].v+t0 (bf16 rows)
__global__ __launch_bounds__(256)
void rowdot2_kernel(const short* __restrict__ Hd, const short* __restrict__ Tl,
                    const float* __restrict__ uv, const float* __restrict__ s0t0,
                    float* __restrict__ ss, float* __restrict__ ts, int N)
{
    int row = blockIdx.x * 4 + (threadIdx.x >> 6);
    int lane = threadIdx.x & 63;
    if (row >= N) return;
    short8v h = ((const short8v*)(Hd + (size_t)row * HH))[lane];
    short8v t = ((const short8v*)(Tl + (size_t)row * HH))[lane];
    const float4* up = (const float4*)uv + lane * 2;
    const float4* vp = (const float4*)(uv + HH) + lane * 2;
    float4 u0 = up[0], u1 = up[1], v0 = vp[0], v1 = vp[1];
    float a = bf2f(h[0])*u0.x + bf2f(h[1])*u0.y + bf2f(h[2])*u0.z + bf2f(h[3])*u0.w
            + bf2f(h[4])*u1.x + bf2f(h[5])*u1.y + bf2f(h[6])*u1.z + bf2f(h[7])*u1.w;
    float b = bf2f(t[0])*v0.x + bf2f(t[1])*v0.y + bf2f(t[2])*v0.z + bf2f(t[3])*v0.w
            + bf2f(t[4])*v1.x + bf2f(t[5])*v1.y + bf2f(t[6])*v1.z + bf2f(t[7])*v1.w;
#pragma unroll
    for (int m = 32; m >= 1; m >>= 1) {
        a += __shfl_xor(a, m);
        b += __shfl_xor(b, m);
    }
    if (lane == 0) { ss[row] = a + s0t0[0]; ts[row] = b + s0t0[1]; }
}

// ---------------- CSR build (both relations, hoisted) ----------------
__global__ __launch_bounds__(256)
void count2_kernel(const int* __restrict__ s0, const int* __restrict__ s1,
                   int* __restrict__ c0, int* __restrict__ c1, int E)
{
    int i = blockIdx.x * blockDim.x + threadIdx.x;
    if (i < E) atomicAdd(&c0[s0[i]], 1);
    else if (i < 2 * E) atomicAdd(&c1[s1[i - E]], 1);
}

__global__ __launch_bounds__(1024)
void scan2_kernel(const int* __restrict__ c0, const int* __restrict__ c1,
                  int* __restrict__ o0, int* __restrict__ o1,
                  int* __restrict__ u0, int* __restrict__ u1, int n)
{
    const int* counts = blockIdx.x ? c1 : c0;
    int* offs = blockIdx.x ? o1 : o0;
    int* curs = blockIdx.x ? u1 : u0;
    __shared__ int part[1024];
    const int tid = threadIdx.x;
    const int CH = (n + 1023) / 1024;
    const int base = tid * CH;
    int s = 0;
    for (int i = 0; i < CH; ++i) {
        int idx = base + i;
        if (idx < n) s += counts[idx];
    }
    part[tid] = s;
    __syncthreads();
    for (int d = 1; d < 1024; d <<= 1) {
        int v = 0;
        if (tid >= d) v = part[tid - d];
        __syncthreads();
        if (tid >= d) part[tid] += v;
        __syncthreads();
    }
    int run = (tid == 0) ? 0 : part[tid - 1];
    for (int i = 0; i < CH; ++i) {
        int idx = base + i;
        if (idx < n) { offs[idx] = run; curs[idx] = run; run += counts[idx]; }
    }
    if (tid == 1023) offs[n] = run;
}

// fill CSR with target ids AND precomputed edge weights
__global__ __launch_bounds__(256)
void fill_kernel(const int* __restrict__ src, const int* __restrict__ tgt,
                 const float* __restrict__ ss, const float* __restrict__ ts,
                 const float* __restrict__ ab_ptr, int* __restrict__ cursor,
                 int* __restrict__ tvals, float* __restrict__ wv, int E)
{
    int i = blockIdx.x * blockDim.x + threadIdx.x;
    if (i >= E) return;
    int s = src[i], t = tgt[i];
    int pos = atomicAdd(&cursor[s], 1);
    tvals[pos] = t;
    wv[pos] = expf(tanhf(ss[s] + ts[t] + ab_ptr[0]));
}

// ---------------- fused GAT aggregate + combine (bf16 rows) -----------------
// out[s,:] = (head[s,:] + (sum_j w_j T[t_j,:]) / (sum_j w_j) + gbias) * 0.5
__global__ __launch_bounds__(256)
void gat_agg_kernel(const int* __restrict__ offs, const int* __restrict__ tvals,
                    const float* __restrict__ wv, const short* __restrict__ T,
                    const short* __restrict__ head, const float* __restrict__ gbias,
                    short* __restrict__ out, int N)
{
    int s = blockIdx.x * 4 + (threadIdx.x >> 6);
    int lane = threadIdx.x & 63;
    if (s >= N) return;
    const int beg = offs[s], end = offs[s + 1];
    float a[8];
#pragma unroll
    for (int q = 0; q < 8; ++q) a[q] = 0.f;
    float den = 0.f;

    int j = beg;
    for (; j + 4 <= end; j += 4) {
        int t0 = tvals[j], t1 = tvals[j + 1], t2 = tvals[j + 2], t3 = tvals[j + 3];
        float w0 = wv[j], w1 = wv[j + 1], w2 = wv[j + 2], w3 = wv[j + 3];
        short8v v0 = ((const short8v*)(T + (size_t)t0 * HH))[lane];
        short8v v1 = ((const short8v*)(T + (size_t)t1 * HH))[lane];
        short8v v2 = ((const short8v*)(T + (size_t)t2 * HH))[lane];
        short8v v3 = ((const short8v*)(T + (size_t)t3 * HH))[lane];
        den += w0 + w1 + w2 + w3;
#pragma unroll
        for (int q = 0; q < 8; ++q) {
            float acc = a[q];
            acc = fmaf(w0, bf2f(v0[q]), acc);
            acc = fmaf(w1, bf2f(v1[q]), acc);
            acc = fmaf(w2, bf2f(v2[q]), acc);
            acc = fmaf(w3, bf2f(v3[q]), acc);
            a[q] = acc;
        }
    }
    for (; j < end; ++j) {
        int t = tvals[j];
        float w = wv[j];
        short8v tv = ((const short8v*)(T + (size_t)t * HH))[lane];
        den += w;
#pragma unroll
        for (int q = 0; q < 8; ++q) a[q] = fmaf(w, bf2f(tv[q]), a[q]);
    }
    float inv = (den > 0.f) ? 1.f / den : 0.f;

    short8v h = ((const short8v*)(head + (size_t)s * HH))[lane];
    const float4* bp = (const float4*)gbias + lane * 2;
    float4 b0 = bp[0], b1 = bp[1];
    float bb[8] = {b0.x, b0.y, b0.z, b0.w, b1.x, b1.y, b1.z, b1.w};
    short8v o;
#pragma unroll
    for (int q = 0; q < 8; ++q)
        o[q] = f2bf((bf2f(h[q]) + a[q] * inv + bb[q]) * 0.5f);
    ((short8v*)(out + (size_t)s * HH))[lane] = o;
}

// ---------------- out = LN(tanh(Z [+ res])) * g + b, row-wise (H=512) -------
__global__ __launch_bounds__(256)
void tanh_ln_kernel(const short* __restrict__ Z, const float* __restrict__ res,
                    const float* __restrict__ g, const float* __restrict__ bta,
                    short* __restrict__ outB, float* __restrict__ outF,
                    const float* __restrict__ cWp, const float* __restrict__ cbp,
                    float* __restrict__ outCls, int N)
{
    int row = blockIdx.x * 4 + (threadIdx.x >> 6);
    int lane = threadIdx.x & 63;
    if (row >= N) return;
    short8v zv = ((const short8v*)(Z + (size_t)row * HH))[lane];
    float v[8];
    float sum = 0.f, sum2 = 0.f;
    float rr[8];
    if (res) {
        const float4* rp = (const float4*)(res + (size_t)row * HH) + lane * 2;
        float4 r0 = rp[0], r1 = rp[1];
        rr[0]=r0.x; rr[1]=r0.y; rr[2]=r0.z; rr[3]=r0.w;
        rr[4]=r1.x; rr[5]=r1.y; rr[6]=r1.z; rr[7]=r1.w;
    } else {
#pragma unroll
        for (int q = 0; q < 8; ++q) rr[q] = 0.f;
    }
#pragma unroll
    for (int q = 0; q < 8; ++q) {
        float t = tanhf(bf2f(zv[q]) + rr[q]);
        v[q] = t;
        sum += t;
        sum2 = fmaf(t, t, sum2);
    }
#pragma unroll
    for (int m = 32; m >= 1; m >>= 1) {
        sum  += __shfl_xor(sum, m);
        sum2 += __shfl_xor(sum2, m);
    }
    float mu  = sum * (1.f/HH);
    float var = sum2 * (1.f/HH) - mu*mu;
    float rs  = rsqrtf(var + 1e-5f);
    const float4* gp = (const float4*)g + lane * 2;
    const float4* bp = (const float4*)bta + lane * 2;
    float4 g0 = gp[0], g1 = gp[1], c0 = bp[0], c1 = bp[1];
    float gg[8] = {g0.x, g0.y, g0.z, g0.w, g1.x, g1.y, g1.z, g1.w};
    float cc[8] = {c0.x, c0.y, c0.z, c0.w, c1.x, c1.y, c1.z, c1.w};
    float o[8];
#pragma unroll
    for (int q = 0; q < 8; ++q) o[q] = (v[q]-mu)*rs*gg[q] + cc[q];
    if (outB) {
        short8v ob;
#pragma unroll
        for (int q = 0; q < 8; ++q) ob[q] = f2bf(o[q]);
        ((short8v*)(outB + (size_t)row * HH))[lane] = ob;
    }
    if (outF) {
        float4* op = (float4*)(outF + (size_t)row * HH) + lane * 2;
        op[0] = make_float4(o[0], o[1], o[2], o[3]);
        op[1] = make_float4(o[4], o[5], o[6], o[7]);
    }
    if (cWp) {
        const float4* wp = (const float4*)cWp + lane * 2;
        float4 w0 = wp[0], w1 = wp[1];
        float acc = o[0]*w0.x + o[1]*w0.y + o[2]*w0.z + o[3]*w0.w
                  + o[4]*w1.x + o[5]*w1.y + o[6]*w1.z + o[7]*w1.w;
#pragma unroll
        for (int m = 32; m >= 1; m >>= 1) acc += __shfl_xor(acc, m);
        if (lane == 0) outCls[row] = 1.f / (1.f + expf(-(acc + cbp[0])));
    }
}

extern "C" void kernel_launch(void* const* d_in, const int* in_sizes, int n_in,
                              void* d_out, int out_size, void* d_ws, size_t ws_size,
                              hipStream_t stream)
{
    (void)in_sizes; (void)n_in; (void)out_size; (void)ws_size;
    const int N = NN, E = NE, H = HH;
    const size_t NHf = (size_t)N * H;

    const float* fu0 = (const float*)d_in[0];
    const float* fi1 = (const float*)d_in[3];
    const float* fu2 = (const float*)d_in[4];
    const int* eUI0 = (const int*)d_in[6];
    const int* eIU1 = (const int*)d_in[9];
    const float* Wu  = (const float*)d_in[10];
    const float* bu  = (const float*)d_in[11];
    const float* Wi  = (const float*)d_in[12];
    const float* bi  = (const float*)d_in[13];
    const float* gfW = (const float*)d_in[14];
    const float* gfb = (const float*)d_in[15];
    const float* gaw = (const float*)d_in[16];
    const float* gab = (const float*)d_in[17];
    const float* gbias = (const float*)d_in[18];
    const float* prW = (const float*)d_in[19];
    const float* prb = (const float*)d_in[20];
    const float* dW  = (const float*)d_in[21];
    const float* db  = (const float*)d_in[22];
    const float* dlg = (const float*)d_in[23];
    const float* dlb = (const float*)d_in[24];
    const float* rlg = (const float*)d_in[25];
    const float* rlb = (const float*)d_in[26];
    const float* cW  = (const float*)d_in[27];
    const float* cb  = (const float*)d_in[28];

    // fp32 region
    float* B5   = (float*)d_ws;      // residual sc (fp32)
    float* ssb  = B5 + NHf;          // [N]
    float* tsb  = ssb + N;           // [N]
    float* uv   = tsb + N;           // [1024]
    float* s0t0 = uv + 1024;         // [2] (+pad)
    float* wvb  = s0t0 + 4;          // [E]
    int* counts0 = (int*)(wvb + E);  // [N]
    int* counts1 = counts0 + N;      // [N]
    int* offs0   = counts1 + N;      // [N+1]
    int* offs1   = offs0 + N + 1;    // [N+1]
    int* cur0    = offs1 + N + 1;    // [N]
    int* cur1    = cur0 + N;         // [N]
    int* tvals   = cur1 + N;         // [E]
    size_t boff = (size_t)((char*)(tvals + E) - (char*)d_ws);
    boff = (boff + 15) & ~(size_t)15;
    // bf16 activations (lifetime-based reuse)
    short* S0    = (short*)((char*)d_ws + boff); // [2*NHf]: fu2 bf16, fu0 bf16
    short* SUHU  = S0 + 2 * NHf;                 // [2*NHf]: su, hu0
    short* XI1   = SUHU + 2 * NHf;               // [NHf/2] raw item feat
    short* HI    = XI1 + NHf / 2;                // hi
    short* SINEW = HI + NHf;                     // si_new ; later XB
    short* T4    = SINEW + NHf;                  // gat tail transform
    short* SUF   = T4 + NHf;                     // su_final
    short* WTu   = SUF + NHf;
    short* WTi   = WTu + 512 * 512;
    short* WTg0  = WTi + 512 * 256;
    short* WTg1  = WTg0 + 512 * 512;
    short* WTpr  = WTg1 + 512 * 512;
    short* WTd   = WTpr + 512 * 512;             // 4 x 512*512
    short* SU  = SUHU;
    short* HU0 = SUHU + NHf;
    short* XB  = SINEW;   // alias after GAT0 done
    short* ZB  = SU;      // alias after both GATs done (SUHU free)

    // ---- weight pre-pass ----
    auto WTR = [&](const float* src, short* dst, int K) {
        hipLaunchKernelGGL(wtr_kernel, dim3(16, K / 32), dim3(32, 8), 0, stream,
                           src, dst, K, 512);
    };
    WTR(Wu, WTu, 512);
    WTR(Wi, WTi, 256);
    WTR(gfW, WTg0, 512);
    WTR(gfW + (size_t)H * H, WTg1, 512);
    WTR(prW, WTpr, 512);
    for (int k = 0; k < 4; ++k)
        WTR(dW + (size_t)k * H * H, WTd + (size_t)k * 512 * 512, 512);

    auto F2B = [&](const float* src, short* dst, size_t n) {
        int n8 = (int)(n / 8);
        hipLaunchKernelGGL(f2b_kernel, dim3((n8 + 255) / 256), dim3(256), 0, stream,
                           src, dst, n8);
    };

    // ---- CSR build ----
    hipMemsetAsync(counts0, 0, 2 * N * sizeof(int), stream);
    hipLaunchKernelGGL(count2_kernel, dim3((2 * E + 255) / 256), dim3(256), 0, stream,
                       eUI0, eIU1, counts0, counts1, E);
    hipLaunchKernelGGL(scan2_kernel, dim3(2), dim3(1024), 0, stream,
                       counts0, counts1, offs0, offs1, cur0, cur1, N);

    auto MLIN = [&](const short* X, const short* WT, const float* b,
                    float* oF, short* oB, int M, int K) {
        int nwg = ((M + 127) / 128) * 8;
        hipLaunchKernelGGL(mfma_lin, dim3(nwg), dim3(256), 0, stream,
                           X, WT, b, oF, oB, M, K);
    };
    const int rgrid = (N + 3) / 4;
    const int egrid = (E + 255) / 256;

    auto GAT = [&](int r, const short* headB, const short* tailB, const short* WTg,
                   const int* edges, int* offs, int* curs, short* outB) {
        hipLaunchKernelGGL(gat_pre_kernel, dim3(130), dim3(256), 0, stream,
                           gfW + (size_t)r * H * H, gfb + r * H, gaw + (size_t)r * 2 * H,
                           uv, s0t0);
        MLIN(tailB, WTg, gfb + r * H, nullptr, T4, N, 512);
        hipLaunchKernelGGL(rowdot2_kernel, dim3(rgrid), dim3(256), 0, stream,
                           headB, tailB, uv, s0t0, ssb, tsb, N);
        hipLaunchKernelGGL(fill_kernel, dim3(egrid), dim3(256), 0, stream,
                           edges, edges + E, ssb, tsb, gab + r, curs, tvals, wvb, E);
        hipLaunchKernelGGL(gat_agg_kernel, dim3(rgrid), dim3(256), 0, stream,
                           offs, tvals, wvb, T4, headB, gbias + (size_t)r * H, outB, N);
    };

    // input transforms (su & hu0 batched: M = 2N over contiguous S0 -> SUHU)
    F2B(fu2, S0, NHf);
    F2B(fu0, S0 + NHf, NHf);
    F2B(fi1, XI1, NHf / 2);
    MLIN(S0, WTu, bu, nullptr, SUHU, 2 * N, 512);     // su + hu0
    MLIN(XI1, WTi, bi, nullptr, HI, N, 256);          // hi
    GAT(1, HI, SU, WTg1, eIU1, offs1, cur1, SINEW);   // si_new
    GAT(0, HU0, SINEW, WTg0, eUI0, offs0, cur0, SUF); // su_final

    // Res_DNN head (MLIN + tanh_ln; prep dual-writes sc fp32)
    MLIN(SUF, WTpr, prb, B5, XB, N, 512);
    for (int r = 0; r < 2; ++r) {
        for (int d = 0; d < 2; ++d) {
            MLIN(XB, WTd + (size_t)(r * 2 + d) * 512 * 512, db + (r * 2 + d) * H,
                 nullptr, ZB, N, 512);
            hipLaunchKernelGGL(tanh_ln_kernel, dim3(rgrid), dim3(256), 0, stream,
                               ZB, (const float*)nullptr, dlg + (r * 2 + d) * H,
                               dlb + (r * 2 + d) * H, XB, (float*)nullptr,
                               (const float*)nullptr, (const float*)nullptr,
                               (float*)nullptr, N);
        }
        if (r == 0) {
            hipLaunchKernelGGL(tanh_ln_kernel, dim3(rgrid), dim3(256), 0, stream,
                               XB, B5, rlg, rlb, XB, B5,
                               (const float*)nullptr, (const float*)nullptr,
                               (float*)nullptr, N);
        } else {
            hipLaunchKernelGGL(tanh_ln_kernel, dim3(rgrid), dim3(256), 0, stream,
                               XB, B5, rlg + H, rlb + H, (short*)nullptr,
                               (float*)nullptr, cW, cb, (float*)d_out, N);
        }
    }
}

// Round 10
// 561.258 us; speedup vs baseline: 1.0908x; 1.0908x over previous
//
#include <hip/hip_runtime.h>
#include <math.h>

#define NN 20000
#define NE 200000
#define HH 512

typedef __attribute__((ext_vector_type(8))) short short8v;
typedef __attribute__((ext_vector_type(4))) float f32x4;

__device__ inline short f2bf(float f) {
    union { float f; unsigned u; } v; v.f = f;
    unsigned r = (v.u + 0x7fffu + ((v.u >> 16) & 1u)) >> 16;
    return (short)r;
}
__device__ inline float bf2f(short s) {
    union { unsigned u; float f; } v;
    v.u = ((unsigned)(unsigned short)s) << 16;
    return v.f;
}

// direct global->LDS DMA, 16B per lane; lds dest must be wave-uniform base
__device__ inline void gload_lds16(const void* g, void* l) {
    __builtin_amdgcn_global_load_lds(
        (const __attribute__((address_space(1))) void*)g,
        (__attribute__((address_space(3))) void*)l, 16, 0, 0);
}

// ---------------- fp32 -> bf16 bulk convert (8 elems/thread) ----------------
__global__ __launch_bounds__(256)
void f2b_kernel(const float* __restrict__ src, short* __restrict__ dst, int n8)
{
    int i = blockIdx.x * 256 + threadIdx.x;
    if (i >= n8) return;
    const float4* p = (const float4*)src + (size_t)i * 2;
    float4 a = p[0], b = p[1];
    short8v s;
    s[0] = f2bf(a.x); s[1] = f2bf(a.y); s[2] = f2bf(a.z); s[3] = f2bf(a.w);
    s[4] = f2bf(b.x); s[5] = f2bf(b.y); s[6] = f2bf(b.z); s[7] = f2bf(b.w);
    ((short8v*)dst)[i] = s;
}

// ---------------- weight transpose + bf16 convert: dst[n][k] = src[k][n] ----
__global__ __launch_bounds__(256)
void wtr_kernel(const float* __restrict__ src, short* __restrict__ dst,
                int K, int Ncols)
{
    __shared__ float t[32][33];
    int bx = blockIdx.x * 32;
    int by = blockIdx.y * 32;
    int tx = threadIdx.x, ty = threadIdx.y;
    for (int i = ty; i < 32; i += 8)
        t[i][tx] = src[(size_t)(by + i) * Ncols + bx + tx];
    __syncthreads();
    for (int i = ty; i < 32; i += 8)
        dst[(size_t)(bx + i) * K + by + tx] = f2bf(t[tx][i]);
}

// ---------------- MFMA GEMM: out[M,512] = X[M,K](bf16) @ WT[512,K](bf16)^T + b
// 128x128 tile, BK=64 (2 sub-steps of 32), 4 waves (2x2), wave 64x64.
// 2-stage double-buffered global_load_lds, counted vmcnt(8); 32 MFMA per
// barrier-pair (halves barrier count vs BK=32).
__global__ __launch_bounds__(256)
void mfma_lin(const short* __restrict__ X, const short* __restrict__ WT,
              const float* __restrict__ bias, float* __restrict__ outF,
              short* __restrict__ outB, int M, int K)
{
    // per stage: A = slots [0,1024) (128 rows x 8 chunks), B = [1024,2048)
    __shared__ short8v pool[4096];   // 2 stages x 2048 slots = 64 KB

    const int tid = threadIdx.x;
    const int lane = tid & 63;
    const int w = tid >> 6;

    const int nby = (M + 127) >> 7;
    const int nwg = nby << 2;
    const int q = nwg >> 3, r = nwg & 7;
    int id = blockIdx.x;
    int xcd = id & 7, wi = id >> 3;
    int wgid = (xcd < r ? xcd * (q + 1) : r * (q + 1) + (xcd - r) * q) + wi;
    const int col0 = (wgid & 3) * 128;
    const int row0 = (wgid >> 2) * 128;

    const int wr = (w >> 1) * 64;
    const int wc = (w & 1) * 64;

    // staging: 2048 slots/stage, 8 per thread (wave w covers [w*512, w*512+512))
    const short* gsrc[8];
#pragma unroll
    for (int g = 0; g < 8; ++g) {
        int p = w * 512 + g * 64 + lane;
        if (p < 1024) {
            int row = p >> 3;
            int c = (p & 7) ^ (row & 7);
            int ga = row0 + row; if (ga >= M) ga = M - 1;
            gsrc[g] = X + (size_t)ga * K + c * 8;
        } else {
            int qq = p - 1024;
            int col = qq >> 3;
            int c = (qq & 7) ^ (col & 7);
            gsrc[g] = WT + (size_t)(col0 + col) * K + c * 8;
        }
    }

    // fragment read indices (8-chunk XOR swizzle), per sub-step kk
    int ar[2][4], br[2][4];
#pragma unroll
    for (int kk = 0; kk < 2; ++kk) {
#pragma unroll
        for (int i = 0; i < 4; ++i) {
            int rr = wr + i * 16 + (lane & 15);
            ar[kk][i] = rr * 8 + ((kk * 4 + (lane >> 4)) ^ (rr & 7));
            int nn = wc + i * 16 + (lane & 15);
            br[kk][i] = 1024 + nn * 8 + ((kk * 4 + (lane >> 4)) ^ (nn & 7));
        }
    }

    f32x4 acc[4][4];
#pragma unroll
    for (int i = 0; i < 4; ++i)
#pragma unroll
        for (int j = 0; j < 4; ++j)
            acc[i][j] = (f32x4){0.f, 0.f, 0.f, 0.f};

    auto stage = [&](int buf, int kk) {
        short8v* base = pool + buf * 2048 + w * 512;
#pragma unroll
        for (int g = 0; g < 8; ++g)
            gload_lds16(gsrc[g] + kk, base + g * 64);
    };

    const int nt = K >> 6;            // 8 (K=512) or 4 (K=256)
    stage(0, 0);
    if (nt > 1) stage(1, 64);
    int cur = 0;
    for (int t = 0; t < nt; ++t) {
        // wait for stage t (8 loads/thread/stage); keep next stage in flight
        if (t + 1 < nt) asm volatile("s_waitcnt vmcnt(8)" ::: "memory");
        else            asm volatile("s_waitcnt vmcnt(0)" ::: "memory");
        __builtin_amdgcn_s_barrier();
        const short8v* S = pool + cur * 2048;
#pragma unroll
        for (int kk = 0; kk < 2; ++kk) {
            short8v af[4], bf[4];
#pragma unroll
            for (int i = 0; i < 4; ++i) af[i] = S[ar[kk][i]];
#pragma unroll
            for (int j = 0; j < 4; ++j) bf[j] = S[br[kk][j]];
#pragma unroll
            for (int i = 0; i < 4; ++i)
#pragma unroll
                for (int j = 0; j < 4; ++j)
                    acc[i][j] = __builtin_amdgcn_mfma_f32_16x16x32_bf16(af[i], bf[j], acc[i][j], 0, 0, 0);
        }
        __builtin_amdgcn_s_barrier();          // all waves done reading buf cur
        if (t + 2 < nt) stage(cur, (t + 2) * 64);
        cur ^= 1;
    }

    float bj[4];
#pragma unroll
    for (int j = 0; j < 4; ++j)
        bj[j] = bias[col0 + wc + j * 16 + (lane & 15)];

    if (outF) {   // fp32 path (prep residual only)
#pragma unroll
        for (int i = 0; i < 4; ++i) {
#pragma unroll
            for (int rr = 0; rr < 4; ++rr) {
                int row = row0 + wr + i * 16 + (lane >> 4) * 4 + rr;
                if (row < M) {
                    float* op = outF + (size_t)row * HH + col0 + wc + (lane & 15);
#pragma unroll
                    for (int j = 0; j < 4; ++j) op[j * 16] = acc[i][j][rr] + bj[j];
                }
            }
        }
    }
    if (outB) {   // bf16: wave-private LDS transpose -> coalesced short8 rows
        short* lds = (short*)pool + w * 4608;   // 64 rows x 72 shorts per wave
#pragma unroll
        for (int i = 0; i < 4; ++i)
#pragma unroll
            for (int rr = 0; rr < 4; ++rr) {
                int lrow = i * 16 + (lane >> 4) * 4 + rr;
#pragma unroll
                for (int j = 0; j < 4; ++j)
                    lds[lrow * 72 + j * 16 + (lane & 15)] = f2bf(acc[i][j][rr] + bj[j]);
            }
#pragma unroll
        for (int k = 0; k < 8; ++k) {
            int lr = (lane >> 3) + 8 * k;
            int lc = (lane & 7) * 8;
            int grow = row0 + wr + lr;
            if (grow < M) {
                short8v vv = *(short8v*)(lds + lr * 72 + lc);
                *(short8v*)(outB + (size_t)grow * HH + col0 + wc + lc) = vv;
            }
        }
    }
}

// ---------------- gat_pre: u = fW @ aw[:512], v = fW @ aw[512:], fb dots -----
__global__ __launch_bounds__(256)
void gat_pre_kernel(const float* __restrict__ fW, const float* __restrict__ fb,
                    const float* __restrict__ aw, float* __restrict__ uv,
                    float* __restrict__ s0t0)
{
    int row = blockIdx.x * 4 + (threadIdx.x >> 6);
    int lane = threadIdx.x & 63;
    const float4* ah = (const float4*)aw;
    const float4* at = (const float4*)(aw + HH);
    const float4* fp;
    if (row < 512)      fp = (const float4*)(fW + (size_t)row * HH);
    else if (row == 512) fp = (const float4*)fb;
    else return;
    float du = 0.f, dv = 0.f;
#pragma unroll
    for (int l = 0; l < 2; ++l) {
        int idx = lane * 2 + l;
        float4 f = fp[idx], a = ah[idx], b = at[idx];
        du += f.x*a.x + f.y*a.y + f.z*a.z + f.w*a.w;
        dv += f.x*b.x + f.y*b.y + f.z*b.z + f.w*b.w;
    }
#pragma unroll
    for (int m = 32; m >= 1; m >>= 1) {
        du += __shfl_xor(du, m);
        dv += __shfl_xor(dv, m);
    }
    if (lane == 0) {
        if (row < 512) { uv[row] = du; uv[512 + row] = dv; }
        else           { s0t0[0] = du; s0t0[1] = dv; }
    }
}

// ---------------- rowdot2: ss[n]=Head[n].u+s0, ts[n]=Tail[n].v+t0 (bf16 rows)
__global__ __launch_bounds__(256)
void rowdot2_kernel(const short* __restrict__ Hd, const short* __restrict__ Tl,
                    const float* __restrict__ uv, const float* __restrict__ s0t0,
                    float* __restrict__ ss, float* __restrict__ ts, int N)
{
    int row = blockIdx.x * 4 + (threadIdx.x >> 6);
    int lane = threadIdx.x & 63;
    if (row >= N) return;
    short8v h = ((const short8v*)(Hd + (size_t)row * HH))[lane];
    short8v t = ((const short8v*)(Tl + (size_t)row * HH))[lane];
    const float4* up = (const float4*)uv + lane * 2;
    const float4* vp = (const float4*)(uv + HH) + lane * 2;
    float4 u0 = up[0], u1 = up[1], v0 = vp[0], v1 = vp[1];
    float a = bf2f(h[0])*u0.x + bf2f(h[1])*u0.y + bf2f(h[2])*u0.z + bf2f(h[3])*u0.w
            + bf2f(h[4])*u1.x + bf2f(h[5])*u1.y + bf2f(h[6])*u1.z + bf2f(h[7])*u1.w;
    float b = bf2f(t[0])*v0.x + bf2f(t[1])*v0.y + bf2f(t[2])*v0.z + bf2f(t[3])*v0.w
            + bf2f(t[4])*v1.x + bf2f(t[5])*v1.y + bf2f(t[6])*v1.z + bf2f(t[7])*v1.w;
#pragma unroll
    for (int m = 32; m >= 1; m >>= 1) {
        a += __shfl_xor(a, m);
        b += __shfl_xor(b, m);
    }
    if (lane == 0) { ss[row] = a + s0t0[0]; ts[row] = b + s0t0[1]; }
}

// ---------------- CSR build (both relations, hoisted) ----------------
__global__ __launch_bounds__(256)
void count2_kernel(const int* __restrict__ s0, const int* __restrict__ s1,
                   int* __restrict__ c0, int* __restrict__ c1, int E)
{
    int i = blockIdx.x * blockDim.x + threadIdx.x;
    if (i < E) atomicAdd(&c0[s0[i]], 1);
    else if (i < 2 * E) atomicAdd(&c1[s1[i - E]], 1);
}

__global__ __launch_bounds__(1024)
void scan2_kernel(const int* __restrict__ c0, const int* __restrict__ c1,
                  int* __restrict__ o0, int* __restrict__ o1,
                  int* __restrict__ u0, int* __restrict__ u1, int n)
{
    const int* counts = blockIdx.x ? c1 : c0;
    int* offs = blockIdx.x ? o1 : o0;
    int* curs = blockIdx.x ? u1 : u0;
    __shared__ int part[1024];
    const int tid = threadIdx.x;
    const int CH = (n + 1023) / 1024;
    const int base = tid * CH;
    int s = 0;
    for (int i = 0; i < CH; ++i) {
        int idx = base + i;
        if (idx < n) s += counts[idx];
    }
    part[tid] = s;
    __syncthreads();
    for (int d = 1; d < 1024; d <<= 1) {
        int v = 0;
        if (tid >= d) v = part[tid - d];
        __syncthreads();
        if (tid >= d) part[tid] += v;
        __syncthreads();
    }
    int run = (tid == 0) ? 0 : part[tid - 1];
    for (int i = 0; i < CH; ++i) {
        int idx = base + i;
        if (idx < n) { offs[idx] = run; curs[idx] = run; run += counts[idx]; }
    }
    if (tid == 1023) offs[n] = run;
}

// fill CSR with target ids AND precomputed edge weights
__global__ __launch_bounds__(256)
void fill_kernel(const int* __restrict__ src, const int* __restrict__ tgt,
                 const float* __restrict__ ss, const float* __restrict__ ts,
                 const float* __restrict__ ab_ptr, int* __restrict__ cursor,
                 int* __restrict__ tvals, float* __restrict__ wv, int E)
{
    int i = blockIdx.x * blockDim.x + threadIdx.x;
    if (i >= E) return;
    int s = src[i], t = tgt[i];
    int pos = atomicAdd(&cursor[s], 1);
    tvals[pos] = t;
    wv[pos] = expf(tanhf(ss[s] + ts[t] + ab_ptr[0]));
}

// ---------------- fused GAT aggregate + combine (bf16 rows) -----------------
// out[s,:] = (head[s,:] + (sum_j w_j T[t_j,:]) / (sum_j w_j) + gbias) * 0.5
__global__ __launch_bounds__(256)
void gat_agg_kernel(const int* __restrict__ offs, const int* __restrict__ tvals,
                    const float* __restrict__ wv, const short* __restrict__ T,
                    const short* __restrict__ head, const float* __restrict__ gbias,
                    short* __restrict__ out, int N)
{
    int s = blockIdx.x * 4 + (threadIdx.x >> 6);
    int lane = threadIdx.x & 63;
    if (s >= N) return;
    const int beg = offs[s], end = offs[s + 1];
    float a[8];
#pragma unroll
    for (int q = 0; q < 8; ++q) a[q] = 0.f;
    float den = 0.f;

    int j = beg;
    for (; j + 4 <= end; j += 4) {
        int t0 = tvals[j], t1 = tvals[j + 1], t2 = tvals[j + 2], t3 = tvals[j + 3];
        float w0 = wv[j], w1 = wv[j + 1], w2 = wv[j + 2], w3 = wv[j + 3];
        short8v v0 = ((const short8v*)(T + (size_t)t0 * HH))[lane];
        short8v v1 = ((const short8v*)(T + (size_t)t1 * HH))[lane];
        short8v v2 = ((const short8v*)(T + (size_t)t2 * HH))[lane];
        short8v v3 = ((const short8v*)(T + (size_t)t3 * HH))[lane];
        den += w0 + w1 + w2 + w3;
#pragma unroll
        for (int q = 0; q < 8; ++q) {
            float acc = a[q];
            acc = fmaf(w0, bf2f(v0[q]), acc);
            acc = fmaf(w1, bf2f(v1[q]), acc);
            acc = fmaf(w2, bf2f(v2[q]), acc);
            acc = fmaf(w3, bf2f(v3[q]), acc);
            a[q] = acc;
        }
    }
    for (; j < end; ++j) {
        int t = tvals[j];
        float w = wv[j];
        short8v tv = ((const short8v*)(T + (size_t)t * HH))[lane];
        den += w;
#pragma unroll
        for (int q = 0; q < 8; ++q) a[q] = fmaf(w, bf2f(tv[q]), a[q]);
    }
    float inv = (den > 0.f) ? 1.f / den : 0.f;

    short8v h = ((const short8v*)(head + (size_t)s * HH))[lane];
    const float4* bp = (const float4*)gbias + lane * 2;
    float4 b0 = bp[0], b1 = bp[1];
    float bb[8] = {b0.x, b0.y, b0.z, b0.w, b1.x, b1.y, b1.z, b1.w};
    short8v o;
#pragma unroll
    for (int q = 0; q < 8; ++q)
        o[q] = f2bf((bf2f(h[q]) + a[q] * inv + bb[q]) * 0.5f);
    ((short8v*)(out + (size_t)s * HH))[lane] = o;
}

// ---------------- out = LN(tanh(Z [+ res])) * g + b, row-wise (H=512) -------
__global__ __launch_bounds__(256)
void tanh_ln_kernel(const short* __restrict__ Z, const float* __restrict__ res,
                    const float* __restrict__ g, const float* __restrict__ bta,
                    short* __restrict__ outB, float* __restrict__ outF,
                    const float* __restrict__ cWp, const float* __restrict__ cbp,
                    float* __restrict__ outCls, int N)
{
    int row = blockIdx.x * 4 + (threadIdx.x >> 6);
    int lane = threadIdx.x & 63;
    if (row >= N) return;
    short8v zv = ((const short8v*)(Z + (size_t)row * HH))[lane];
    float v[8];
    float sum = 0.f, sum2 = 0.f;
    float rr[8];
    if (res) {
        const float4* rp = (const float4*)(res + (size_t)row * HH) + lane * 2;
        float4 r0 = rp[0], r1 = rp[1];
        rr[0]=r0.x; rr[1]=r0.y; rr[2]=r0.z; rr[3]=r0.w;
        rr[4]=r1.x; rr[5]=r1.y; rr[6]=r1.z; rr[7]=r1.w;
    } else {
#pragma unroll
        for (int q = 0; q < 8; ++q) rr[q] = 0.f;
    }
#pragma unroll
    for (int q = 0; q < 8; ++q) {
        float t = tanhf(bf2f(zv[q]) + rr[q]);
        v[q] = t;
        sum += t;
        sum2 = fmaf(t, t, sum2);
    }
#pragma unroll
    for (int m = 32; m >= 1; m >>= 1) {
        sum  += __shfl_xor(sum, m);
        sum2 += __shfl_xor(sum2, m);
    }
    float mu  = sum * (1.f/HH);
    float var = sum2 * (1.f/HH) - mu*mu;
    float rs  = rsqrtf(var + 1e-5f);
    const float4* gp = (const float4*)g + lane * 2;
    const float4* bp = (const float4*)bta + lane * 2;
    float4 g0 = gp[0], g1 = gp[1], c0 = bp[0], c1 = bp[1];
    float gg[8] = {g0.x, g0.y, g0.z, g0.w, g1.x, g1.y, g1.z, g1.w};
    float cc[8] = {c0.x, c0.y, c0.z, c0.w, c1.x, c1.y, c1.z, c1.w};
    float o[8];
#pragma unroll
    for (int q = 0; q < 8; ++q) o[q] = (v[q]-mu)*rs*gg[q] + cc[q];
    if (outB) {
        short8v ob;
#pragma unroll
        for (int q = 0; q < 8; ++q) ob[q] = f2bf(o[q]);
        ((short8v*)(outB + (size_t)row * HH))[lane] = ob;
    }
    if (outF) {
        float4* op = (float4*)(outF + (size_t)row * HH) + lane * 2;
        op[0] = make_float4(o[0], o[1], o[2], o[3]);
        op[1] = make_float4(o[4], o[5], o[6], o[7]);
    }
    if (cWp) {
        const float4* wp = (const float4*)cWp + lane * 2;
        float4 w0 = wp[0], w1 = wp[1];
        float acc = o[0]*w0.x + o[1]*w0.y + o[2]*w0.z + o[3]*w0.w
                  + o[4]*w1.x + o[5]*w1.y + o[6]*w1.z + o[7]*w1.w;
#pragma unroll
        for (int m = 32; m >= 1; m >>= 1) acc += __shfl_xor(acc, m);
        if (lane == 0) outCls[row] = 1.f / (1.f + expf(-(acc + cbp[0])));
    }
}

extern "C" void kernel_launch(void* const* d_in, const int* in_sizes, int n_in,
                              void* d_out, int out_size, void* d_ws, size_t ws_size,
                              hipStream_t stream)
{
    (void)in_sizes; (void)n_in; (void)out_size; (void)ws_size;
    const int N = NN, E = NE, H = HH;
    const size_t NHf = (size_t)N * H;

    const float* fu0 = (const float*)d_in[0];
    const float* fi1 = (const float*)d_in[3];
    const float* fu2 = (const float*)d_in[4];
    const int* eUI0 = (const int*)d_in[6];
    const int* eIU1 = (const int*)d_in[9];
    const float* Wu  = (const float*)d_in[10];
    const float* bu  = (const float*)d_in[11];
    const float* Wi  = (const float*)d_in[12];
    const float* bi  = (const float*)d_in[13];
    const float* gfW = (const float*)d_in[14];
    const float* gfb = (const float*)d_in[15];
    const float* gaw = (const float*)d_in[16];
    const float* gab = (const float*)d_in[17];
    const float* gbias = (const float*)d_in[18];
    const float* prW = (const float*)d_in[19];
    const float* prb = (const float*)d_in[20];
    const float* dW  = (const float*)d_in[21];
    const float* db  = (const float*)d_in[22];
    const float* dlg = (const float*)d_in[23];
    const float* dlb = (const float*)d_in[24];
    const float* rlg = (const float*)d_in[25];
    const float* rlb = (const float*)d_in[26];
    const float* cW  = (const float*)d_in[27];
    const float* cb  = (const float*)d_in[28];

    // fp32 region
    float* B5   = (float*)d_ws;      // residual sc (fp32)
    float* ssb  = B5 + NHf;          // [N]
    float* tsb  = ssb + N;           // [N]
    float* uv   = tsb + N;           // [1024]
    float* s0t0 = uv + 1024;         // [2] (+pad)
    float* wvb  = s0t0 + 4;          // [E]
    int* counts0 = (int*)(wvb + E);  // [N]
    int* counts1 = counts0 + N;      // [N]
    int* offs0   = counts1 + N;      // [N+1]
    int* offs1   = offs0 + N + 1;    // [N+1]
    int* cur0    = offs1 + N + 1;    // [N]
    int* cur1    = cur0 + N;         // [N]
    int* tvals   = cur1 + N;         // [E]
    size_t boff = (size_t)((char*)(tvals + E) - (char*)d_ws);
    boff = (boff + 15) & ~(size_t)15;
    // bf16 activations (lifetime-based reuse)
    short* S0    = (short*)((char*)d_ws + boff); // [2*NHf]: fu2 bf16, fu0 bf16
    short* SUHU  = S0 + 2 * NHf;                 // [2*NHf]: su, hu0
    short* XI1   = SUHU + 2 * NHf;               // [NHf/2] raw item feat
    short* HI    = XI1 + NHf / 2;                // hi
    short* SINEW = HI + NHf;                     // si_new ; later XB
    short* T4    = SINEW + NHf;                  // gat tail transform
    short* SUF   = T4 + NHf;                     // su_final
    short* WTu   = SUF + NHf;
    short* WTi   = WTu + 512 * 512;
    short* WTg0  = WTi + 512 * 256;
    short* WTg1  = WTg0 + 512 * 512;
    short* WTpr  = WTg1 + 512 * 512;
    short* WTd   = WTpr + 512 * 512;             // 4 x 512*512
    short* SU  = SUHU;
    short* HU0 = SUHU + NHf;
    short* XB  = SINEW;   // alias after GAT0 done
    short* ZB  = SU;      // alias after both GATs done (SUHU free)

    // ---- weight pre-pass ----
    auto WTR = [&](const float* src, short* dst, int K) {
        hipLaunchKernelGGL(wtr_kernel, dim3(16, K / 32), dim3(32, 8), 0, stream,
                           src, dst, K, 512);
    };
    WTR(Wu, WTu, 512);
    WTR(Wi, WTi, 256);
    WTR(gfW, WTg0, 512);
    WTR(gfW + (size_t)H * H, WTg1, 512);
    WTR(prW, WTpr, 512);
    for (int k = 0; k < 4; ++k)
        WTR(dW + (size_t)k * H * H, WTd + (size_t)k * 512 * 512, 512);

    auto F2B = [&](const float* src, short* dst, size_t n) {
        int n8 = (int)(n / 8);
        hipLaunchKernelGGL(f2b_kernel, dim3((n8 + 255) / 256), dim3(256), 0, stream,
                           src, dst, n8);
    };

    // ---- CSR build ----
    hipMemsetAsync(counts0, 0, 2 * N * sizeof(int), stream);
    hipLaunchKernelGGL(count2_kernel, dim3((2 * E + 255) / 256), dim3(256), 0, stream,
                       eUI0, eIU1, counts0, counts1, E);
    hipLaunchKernelGGL(scan2_kernel, dim3(2), dim3(1024), 0, stream,
                       counts0, counts1, offs0, offs1, cur0, cur1, N);

    auto MLIN = [&](const short* X, const short* WT, const float* b,
                    float* oF, short* oB, int M, int K) {
        int nwg = ((M + 127) / 128) * 4;
        hipLaunchKernelGGL(mfma_lin, dim3(nwg), dim3(256), 0, stream,
                           X, WT, b, oF, oB, M, K);
    };
    const int rgrid = (N + 3) / 4;
    const int egrid = (E + 255) / 256;

    auto GAT = [&](int r, const short* headB, const short* tailB, const short* WTg,
                   const int* edges, int* offs, int* curs, short* outB) {
        hipLaunchKernelGGL(gat_pre_kernel, dim3(130), dim3(256), 0, stream,
                           gfW + (size_t)r * H * H, gfb + r * H, gaw + (size_t)r * 2 * H,
                           uv, s0t0);
        MLIN(tailB, WTg, gfb + r * H, nullptr, T4, N, 512);
        hipLaunchKernelGGL(rowdot2_kernel, dim3(rgrid), dim3(256), 0, stream,
                           headB, tailB, uv, s0t0, ssb, tsb, N);
        hipLaunchKernelGGL(fill_kernel, dim3(egrid), dim3(256), 0, stream,
                           edges, edges + E, ssb, tsb, gab + r, curs, tvals, wvb, E);
        hipLaunchKernelGGL(gat_agg_kernel, dim3(rgrid), dim3(256), 0, stream,
                           offs, tvals, wvb, T4, headB, gbias + (size_t)r * H, outB, N);
    };

    // input transforms (su & hu0 batched: M = 2N over contiguous S0 -> SUHU)
    F2B(fu2, S0, NHf);
    F2B(fu0, S0 + NHf, NHf);
    F2B(fi1, XI1, NHf / 2);
    MLIN(S0, WTu, bu, nullptr, SUHU, 2 * N, 512);     // su + hu0
    MLIN(XI1, WTi, bi, nullptr, HI, N, 256);          // hi
    GAT(1, HI, SU, WTg1, eIU1, offs1, cur1, SINEW);   // si_new
    GAT(0, HU0, SINEW, WTg0, eUI0, offs0, cur0, SUF); // su_final

    // Res_DNN head (MLIN + tanh_ln; prep dual-writes sc fp32)
    MLIN(SUF, WTpr, prb, B5, XB, N, 512);
    for (int r = 0; r < 2; ++r) {
        for (int d = 0; d < 2; ++d) {
            MLIN(XB, WTd + (size_t)(r * 2 + d) * 512 * 512, db + (r * 2 + d) * H,
                 nullptr, ZB, N, 512);
            hipLaunchKernelGGL(tanh_ln_kernel, dim3(rgrid), dim3(256), 0, stream,
                               ZB, (const float*)nullptr, dlg + (r * 2 + d) * H,
                               dlb + (r * 2 + d) * H, XB, (float*)nullptr,
                               (const float*)nullptr, (const float*)nullptr,
                               (float*)nullptr, N);
        }
        if (r == 0) {
            hipLaunchKernelGGL(tanh_ln_kernel, dim3(rgrid), dim3(256), 0, stream,
                               XB, B5, rlg, rlb, XB, B5,
                               (const float*)nullptr, (const float*)nullptr,
                               (float*)nullptr, N);
        } else {
            hipLaunchKernelGGL(tanh_ln_kernel, dim3(rgrid), dim3(256), 0, stream,
                               XB, B5, rlg + H, rlb + H, (short*)nullptr,
                               (float*)nullptr, cW, cb, (float*)d_out, N);
        }
    }
}

// Round 12
// 516.068 us; speedup vs baseline: 1.1864x; 1.0876x over previous
//
#include <hip/hip_runtime.h>
#include <math.h>

#define NN 20000
#define NE 200000
#define HH 512

typedef __attribute__((ext_vector_type(8))) short short8v;
typedef __attribute__((ext_vector_type(4))) float f32x4;

__device__ inline short f2bf(float f) {
    union { float f; unsigned u; } v; v.f = f;
    unsigned r = (v.u + 0x7fffu + ((v.u >> 16) & 1u)) >> 16;
    return (short)r;
}
__device__ inline float bf2f(short s) {
    union { unsigned u; float f; } v;
    v.u = ((unsigned)(unsigned short)s) << 16;
    return v.f;
}

__device__ inline void gload_lds16(const void* g, void* l) {
    __builtin_amdgcn_global_load_lds(
        (const __attribute__((address_space(1))) void*)g,
        (__attribute__((address_space(3))) void*)l, 16, 0, 0);
}

// ---------------- batched fp32->bf16 convert (3 segments, one launch) -------
__global__ __launch_bounds__(256)
void f2b_all(const float* __restrict__ fu2, const float* __restrict__ fu0,
             const float* __restrict__ fi1, short* __restrict__ S0,
             short* __restrict__ XI1, int nh8)
{
    int i = blockIdx.x * 256 + threadIdx.x;
    const float* src; short* dst; int off;
    if (i < nh8)            { src = fu2; dst = S0;                    off = i; }
    else if (i < 2 * nh8)   { src = fu0; dst = S0 + (size_t)nh8 * 8;  off = i - nh8; }
    else if (i < 2 * nh8 + nh8 / 2) { src = fi1; dst = XI1;           off = i - 2 * nh8; }
    else return;
    const float4* p = (const float4*)src + (size_t)off * 2;
    float4 a = p[0], b = p[1];
    short8v s;
    s[0] = f2bf(a.x); s[1] = f2bf(a.y); s[2] = f2bf(a.z); s[3] = f2bf(a.w);
    s[4] = f2bf(b.x); s[5] = f2bf(b.y); s[6] = f2bf(b.z); s[7] = f2bf(b.w);
    ((short8v*)dst)[off] = s;
}

// ---------------- batched weight transpose+bf16 (9 weights, one launch) -----
__global__ __launch_bounds__(256)
void wtr_all(const float* __restrict__ Wu, const float* __restrict__ Wi,
             const float* __restrict__ gfW, const float* __restrict__ prW,
             const float* __restrict__ dW,
             short* __restrict__ WTu, short* __restrict__ WTi,
             short* __restrict__ WTg0, short* __restrict__ WTg1,
             short* __restrict__ WTpr, short* __restrict__ WTd)
{
    __shared__ float t[32][33];
    int z = blockIdx.z;
    const float* src; short* dst; int K;
    if (z == 0)      { src = Wu;  dst = WTu;  K = 512; }
    else if (z == 1) { src = Wi;  dst = WTi;  K = 256; }
    else if (z == 2) { src = gfW; dst = WTg0; K = 512; }
    else if (z == 3) { src = gfW + (size_t)512 * 512; dst = WTg1; K = 512; }
    else if (z == 4) { src = prW; dst = WTpr; K = 512; }
    else { src = dW + (size_t)(z - 5) * 512 * 512;
           dst = WTd + (size_t)(z - 5) * 512 * 512; K = 512; }
    int by = blockIdx.y * 32;
    if (by >= K) return;
    int bx = blockIdx.x * 32;
    int tx = threadIdx.x, ty = threadIdx.y;
    for (int i = ty; i < 32; i += 8)
        t[i][tx] = src[(size_t)(by + i) * 512 + bx + tx];
    __syncthreads();
    for (int i = ty; i < 32; i += 8)
        dst[(size_t)(bx + i) * K + by + tx] = f2bf(t[tx][i]);
}

// ---------------- MFMA GEMM (128x128, BK=64, 2-stage counted vmcnt) ---------
// + optional rowdot tail blocks (id >= gemm grid): ss/ts attention dots.
__global__ __launch_bounds__(256)
void mfma_lin(const short* __restrict__ X, const short* __restrict__ WT,
              const float* __restrict__ bias, float* __restrict__ outF,
              short* __restrict__ outB, int M, int K,
              const short* __restrict__ rdH, const short* __restrict__ rdT,
              const float* __restrict__ rduv, const float* __restrict__ rds0,
              float* __restrict__ rdss, float* __restrict__ rdts, int rdN)
{
    __shared__ short8v pool[4096];   // 2 stages x 2048 slots = 64 KB

    const int tid = threadIdx.x;
    const int lane = tid & 63;
    const int w = tid >> 6;

    const int nby = (M + 127) >> 7;
    const int nwg = nby << 2;
    int id = blockIdx.x;

    if (id >= nwg) {                 // ---------- rowdot role ----------
        int row = (id - nwg) * 4 + w;
        if (row >= rdN) return;
        short8v h = ((const short8v*)(rdH + (size_t)row * HH))[lane];
        short8v t = ((const short8v*)(rdT + (size_t)row * HH))[lane];
        const float4* up = (const float4*)rduv + lane * 2;
        const float4* vp = (const float4*)(rduv + HH) + lane * 2;
        float4 u0 = up[0], u1 = up[1], v0 = vp[0], v1 = vp[1];
        float a = bf2f(h[0])*u0.x + bf2f(h[1])*u0.y + bf2f(h[2])*u0.z + bf2f(h[3])*u0.w
                + bf2f(h[4])*u1.x + bf2f(h[5])*u1.y + bf2f(h[6])*u1.z + bf2f(h[7])*u1.w;
        float b = bf2f(t[0])*v0.x + bf2f(t[1])*v0.y + bf2f(t[2])*v0.z + bf2f(t[3])*v0.w
                + bf2f(t[4])*v1.x + bf2f(t[5])*v1.y + bf2f(t[6])*v1.z + bf2f(t[7])*v1.w;
#pragma unroll
        for (int m = 32; m >= 1; m >>= 1) {
            a += __shfl_xor(a, m);
            b += __shfl_xor(b, m);
        }
        if (lane == 0) { rdss[row] = a + rds0[0]; rdts[row] = b + rds0[1]; }
        return;
    }

    // ---------- GEMM role ----------
    const int q = nwg >> 3, r = nwg & 7;
    int xcd = id & 7, wi = id >> 3;
    int wgid = (xcd < r ? xcd * (q + 1) : r * (q + 1) + (xcd - r) * q) + wi;
    const int col0 = (wgid & 3) * 128;
    const int row0 = (wgid >> 2) * 128;

    const int wr = (w >> 1) * 64;
    const int wc = (w & 1) * 64;

    const short* gsrc[8];
#pragma unroll
    for (int g = 0; g < 8; ++g) {
        int p = w * 512 + g * 64 + lane;
        if (p < 1024) {
            int row = p >> 3;
            int c = (p & 7) ^ (row & 7);
            int ga = row0 + row; if (ga >= M) ga = M - 1;
            gsrc[g] = X + (size_t)ga * K + c * 8;
        } else {
            int qq = p - 1024;
            int col = qq >> 3;
            int c = (qq & 7) ^ (col & 7);
            gsrc[g] = WT + (size_t)(col0 + col) * K + c * 8;
        }
    }

    int ar[2][4], br[2][4];
#pragma unroll
    for (int kk = 0; kk < 2; ++kk) {
#pragma unroll
        for (int i = 0; i < 4; ++i) {
            int rr = wr + i * 16 + (lane & 15);
            ar[kk][i] = rr * 8 + ((kk * 4 + (lane >> 4)) ^ (rr & 7));
            int nn = wc + i * 16 + (lane & 15);
            br[kk][i] = 1024 + nn * 8 + ((kk * 4 + (lane >> 4)) ^ (nn & 7));
        }
    }

    f32x4 acc[4][4];
#pragma unroll
    for (int i = 0; i < 4; ++i)
#pragma unroll
        for (int j = 0; j < 4; ++j)
            acc[i][j] = (f32x4){0.f, 0.f, 0.f, 0.f};

    auto stage = [&](int buf, int kk) {
        short8v* base = pool + buf * 2048 + w * 512;
#pragma unroll
        for (int g = 0; g < 8; ++g)
            gload_lds16(gsrc[g] + kk, base + g * 64);
    };

    const int nt = K >> 6;
    stage(0, 0);
    if (nt > 1) stage(1, 64);
    int cur = 0;
    for (int t = 0; t < nt; ++t) {
        if (t + 1 < nt) asm volatile("s_waitcnt vmcnt(8)" ::: "memory");
        else            asm volatile("s_waitcnt vmcnt(0)" ::: "memory");
        __builtin_amdgcn_s_barrier();
        const short8v* S = pool + cur * 2048;
#pragma unroll
        for (int kk = 0; kk < 2; ++kk) {
            short8v af[4], bf[4];
#pragma unroll
            for (int i = 0; i < 4; ++i) af[i] = S[ar[kk][i]];
#pragma unroll
            for (int j = 0; j < 4; ++j) bf[j] = S[br[kk][j]];
#pragma unroll
            for (int i = 0; i < 4; ++i)
#pragma unroll
                for (int j = 0; j < 4; ++j)
                    acc[i][j] = __builtin_amdgcn_mfma_f32_16x16x32_bf16(af[i], bf[j], acc[i][j], 0, 0, 0);
        }
        __builtin_amdgcn_s_barrier();
        if (t + 2 < nt) stage(cur, (t + 2) * 64);
        cur ^= 1;
    }

    float bj[4];
#pragma unroll
    for (int j = 0; j < 4; ++j)
        bj[j] = bias[col0 + wc + j * 16 + (lane & 15)];

    if (outF) {   // fp32 dual-write (prep residual only)
#pragma unroll
        for (int i = 0; i < 4; ++i) {
#pragma unroll
            for (int rr = 0; rr < 4; ++rr) {
                int row = row0 + wr + i * 16 + (lane >> 4) * 4 + rr;
                if (row < M) {
                    float* op = outF + (size_t)row * HH + col0 + wc + (lane & 15);
#pragma unroll
                    for (int j = 0; j < 4; ++j) op[j * 16] = acc[i][j][rr] + bj[j];
                }
            }
        }
    }
    if (outB) {   // block-cooperative bf16 epilogue: full 256B-run stores
        short* lt = (short*)pool;    // [128][128] bf16 = 32 KB
#pragma unroll
        for (int i = 0; i < 4; ++i)
#pragma unroll
            for (int rr = 0; rr < 4; ++rr) {
                int lrow = wr + i * 16 + (lane >> 4) * 4 + rr;
#pragma unroll
                for (int j = 0; j < 4; ++j)
                    lt[lrow * 128 + wc + j * 16 + (lane & 15)] = f2bf(acc[i][j][rr] + bj[j]);
            }
        __syncthreads();
#pragma unroll
        for (int k = 0; k < 8; ++k) {
            int row = (tid >> 4) + 16 * k;
            int seg = tid & 15;
            int grow = row0 + row;
            if (grow < M) {
                short8v vv = *(short8v*)(lt + row * 128 + seg * 8);
                *(short8v*)(outB + (size_t)grow * HH + col0 + seg * 8) = vv;
            }
        }
    }
}

// ---------------- gat_pre for BOTH relations (one launch) -------------------
__global__ __launch_bounds__(256)
void gat_pre2(const float* __restrict__ gfW, const float* __restrict__ gfb,
              const float* __restrict__ gaw, float* __restrict__ uvall,
              float* __restrict__ s0t0all)
{
    int rrel = blockIdx.y;
    const float* fW = gfW + (size_t)rrel * HH * HH;
    const float* fb = gfb + rrel * HH;
    const float* aw = gaw + (size_t)rrel * 2 * HH;
    float* uv = uvall + rrel * 1024;
    float* s0t0 = s0t0all + rrel * 4;
    int row = blockIdx.x * 4 + (threadIdx.x >> 6);
    int lane = threadIdx.x & 63;
    const float4* ah = (const float4*)aw;
    const float4* at = (const float4*)(aw + HH);
    const float4* fp;
    if (row < 512)       fp = (const float4*)(fW + (size_t)row * HH);
    else if (row == 512) fp = (const float4*)fb;
    else return;
    float du = 0.f, dv = 0.f;
#pragma unroll
    for (int l = 0; l < 2; ++l) {
        int idx = lane * 2 + l;
        float4 f = fp[idx], a = ah[idx], b = at[idx];
        du += f.x*a.x + f.y*a.y + f.z*a.z + f.w*a.w;
        dv += f.x*b.x + f.y*b.y + f.z*b.z + f.w*b.w;
    }
#pragma unroll
    for (int m = 32; m >= 1; m >>= 1) {
        du += __shfl_xor(du, m);
        dv += __shfl_xor(dv, m);
    }
    if (lane == 0) {
        if (row < 512) { uv[row] = du; uv[512 + row] = dv; }
        else           { s0t0[0] = du; s0t0[1] = dv; }
    }
}

// ---------------- CSR build ----------------
__global__ __launch_bounds__(256)
void count2_kernel(const int* __restrict__ s0, const int* __restrict__ s1,
                   int* __restrict__ c0, int* __restrict__ c1, int E)
{
    int i = blockIdx.x * blockDim.x + threadIdx.x;
    if (i < E) atomicAdd(&c0[s0[i]], 1);
    else if (i < 2 * E) atomicAdd(&c1[s1[i - E]], 1);
}

__global__ __launch_bounds__(1024)
void scan2_kernel(const int* __restrict__ c0, const int* __restrict__ c1,
                  int* __restrict__ o0, int* __restrict__ o1,
                  int* __restrict__ u0, int* __restrict__ u1, int n)
{
    const int* counts = blockIdx.x ? c1 : c0;
    int* offs = blockIdx.x ? o1 : o0;
    int* curs = blockIdx.x ? u1 : u0;
    __shared__ int part[1024];
    const int tid = threadIdx.x;
    const int CH = (n + 1023) / 1024;
    const int base = tid * CH;
    int s = 0;
    for (int i = 0; i < CH; ++i) {
        int idx = base + i;
        if (idx < n) s += counts[idx];
    }
    part[tid] = s;
    __syncthreads();
    for (int d = 1; d < 1024; d <<= 1) {
        int v = 0;
        if (tid >= d) v = part[tid - d];
        __syncthreads();
        if (tid >= d) part[tid] += v;
        __syncthreads();
    }
    int run = (tid == 0) ? 0 : part[tid - 1];
    for (int i = 0; i < CH; ++i) {
        int idx = base + i;
        if (idx < n) { offs[idx] = run; curs[idx] = run; run += counts[idx]; }
    }
    if (tid == 1023) offs[n] = run;
}

// fill CSR: target ids, edge weights, and ORIGINAL EDGE INDEX (for canonical sort)
__global__ __launch_bounds__(256)
void fill_kernel(const int* __restrict__ src, const int* __restrict__ tgt,
                 const float* __restrict__ ss, const float* __restrict__ ts,
                 const float* __restrict__ ab_ptr, int* __restrict__ cursor,
                 int* __restrict__ tvals, float* __restrict__ wv,
                 int* __restrict__ eidx, int E)
{
    int i = blockIdx.x * blockDim.x + threadIdx.x;
    if (i >= E) return;
    int s = src[i], t = tgt[i];
    int pos = atomicAdd(&cursor[s], 1);
    tvals[pos] = t;
    wv[pos] = expf(tanhf(ss[s] + ts[t] + ab_ptr[0]));
    eidx[pos] = i;
}

// ---------------- canonical bucket sort (determinism): sort each node's ----
// CSR bucket by original edge index. One wave per node; eidx stays pristine.
__global__ __launch_bounds__(256)
void sortbkt_kernel(const int* __restrict__ offs, int* __restrict__ tvals,
                    float* __restrict__ wv, const int* __restrict__ eidx, int N)
{
    __shared__ int   lt[4][512];
    __shared__ float lw[4][512];
    int w = threadIdx.x >> 6, lane = threadIdx.x & 63;
    int s = blockIdx.x * 4 + w;
    if (s >= N) return;
    int beg = offs[s], end = offs[s + 1];
    int L = end - beg;
    if (L <= 1) return;
    if (L <= 64) {
        int e = 0x7fffffff, t = 0; float fw = 0.f;
        if (lane < L) { e = eidx[beg + lane]; t = tvals[beg + lane]; fw = wv[beg + lane]; }
        int r = 0;
        for (int k = 0; k < L; ++k) {
            int ek = __shfl(e, k);
            r += (ek < e) ? 1 : 0;
        }
        if (lane < L) { tvals[beg + r] = t; wv[beg + r] = fw; }
    } else if (L <= 512) {
        for (int j = lane; j < L; j += 64) { lt[w][j] = tvals[beg + j]; lw[w][j] = wv[beg + j]; }
        asm volatile("s_waitcnt lgkmcnt(0) vmcnt(0)" ::: "memory");
        for (int j = lane; j < L; j += 64) {
            int e = eidx[beg + j];
            int r = 0;
            for (int k = 0; k < L; ++k) r += (eidx[beg + k] < e) ? 1 : 0;
            tvals[beg + r] = lt[w][j]; wv[beg + r] = lw[w][j];
        }
    }
    // L > 512: left in fill order (values still correct; not hit for this data)
}

// ---------------- fused GAT aggregate + combine (bf16 rows) -----------------
__global__ __launch_bounds__(256)
void gat_agg_kernel(const int* __restrict__ offs, const int* __restrict__ tvals,
                    const float* __restrict__ wv, const short* __restrict__ T,
                    const short* __restrict__ head, const float* __restrict__ gbias,
                    short* __restrict__ out, int N)
{
    int s = blockIdx.x * 4 + (threadIdx.x >> 6);
    int lane = threadIdx.x & 63;
    if (s >= N) return;
    const int beg = offs[s], end = offs[s + 1];
    float a[8];
#pragma unroll
    for (int q = 0; q < 8; ++q) a[q] = 0.f;
    float den = 0.f;

    int j = beg;
    for (; j + 4 <= end; j += 4) {
        int t0 = tvals[j], t1 = tvals[j + 1], t2 = tvals[j + 2], t3 = tvals[j + 3];
        float w0 = wv[j], w1 = wv[j + 1], w2 = wv[j + 2], w3 = wv[j + 3];
        short8v v0 = ((const short8v*)(T + (size_t)t0 * HH))[lane];
        short8v v1 = ((const short8v*)(T + (size_t)t1 * HH))[lane];
        short8v v2 = ((const short8v*)(T + (size_t)t2 * HH))[lane];
        short8v v3 = ((const short8v*)(T + (size_t)t3 * HH))[lane];
        den += w0 + w1 + w2 + w3;
#pragma unroll
        for (int q = 0; q < 8; ++q) {
            float acc = a[q];
            acc = fmaf(w0, bf2f(v0[q]), acc);
            acc = fmaf(w1, bf2f(v1[q]), acc);
            acc = fmaf(w2, bf2f(v2[q]), acc);
            acc = fmaf(w3, bf2f(v3[q]), acc);
            a[q] = acc;
        }
    }
    for (; j < end; ++j) {
        int t = tvals[j];
        float w = wv[j];
        short8v tv = ((const short8v*)(T + (size_t)t * HH))[lane];
        den += w;
#pragma unroll
        for (int q = 0; q < 8; ++q) a[q] = fmaf(w, bf2f(tv[q]), a[q]);
    }
    float inv = (den > 0.f) ? 1.f / den : 0.f;

    short8v h = ((const short8v*)(head + (size_t)s * HH))[lane];
    const float4* bp = (const float4*)gbias + lane * 2;
    float4 b0 = bp[0], b1 = bp[1];
    float bb[8] = {b0.x, b0.y, b0.z, b0.w, b1.x, b1.y, b1.z, b1.w};
    short8v o;
#pragma unroll
    for (int q = 0; q < 8; ++q)
        o[q] = f2bf((bf2f(h[q]) + a[q] * inv + bb[q]) * 0.5f);
    ((short8v*)(out + (size_t)s * HH))[lane] = o;
}

// ---------------- single tanh+LN (d=0 layers): out = LN(tanh(Z))*g+b --------
__global__ __launch_bounds__(256)
void tanh_ln_kernel(const short* __restrict__ Z,
                    const float* __restrict__ g, const float* __restrict__ bta,
                    short* __restrict__ outB, int N)
{
    int row = blockIdx.x * 4 + (threadIdx.x >> 6);
    int lane = threadIdx.x & 63;
    if (row >= N) return;
    short8v zv = ((const short8v*)(Z + (size_t)row * HH))[lane];
    float v[8];
    float sum = 0.f, sum2 = 0.f;
#pragma unroll
    for (int q = 0; q < 8; ++q) {
        float t = tanhf(bf2f(zv[q]));
        v[q] = t; sum += t; sum2 = fmaf(t, t, sum2);
    }
#pragma unroll
    for (int m = 32; m >= 1; m >>= 1) {
        sum += __shfl_xor(sum, m); sum2 += __shfl_xor(sum2, m);
    }
    float mu = sum * (1.f/HH);
    float rs = rsqrtf(sum2 * (1.f/HH) - mu*mu + 1e-5f);
    const float4* gp = (const float4*)g + lane * 2;
    const float4* bp = (const float4*)bta + lane * 2;
    float4 g0 = gp[0], g1 = gp[1], c0 = bp[0], c1 = bp[1];
    float gg[8] = {g0.x, g0.y, g0.z, g0.w, g1.x, g1.y, g1.z, g1.w};
    float cc[8] = {c0.x, c0.y, c0.z, c0.w, c1.x, c1.y, c1.z, c1.w};
    short8v ob;
#pragma unroll
    for (int q = 0; q < 8; ++q) ob[q] = f2bf((v[q]-mu)*rs*gg[q] + cc[q]);
    ((short8v*)(outB + (size_t)row * HH))[lane] = ob;
}

// ---------------- fused double LN (d=1 + residual): ------------------------
// x2 = LN1(tanh(Z))*g1+b1 ; y = LN2(tanh(sc + x2))*g2+b2
__global__ __launch_bounds__(256)
void tanh_ln2_kernel(const short* __restrict__ Z, const float* __restrict__ sc,
                     const float* __restrict__ g1, const float* __restrict__ b1,
                     const float* __restrict__ g2, const float* __restrict__ b2,
                     short* __restrict__ outB, float* __restrict__ outF,
                     const float* __restrict__ cWp, const float* __restrict__ cbp,
                     float* __restrict__ outCls, int N)
{
    int row = blockIdx.x * 4 + (threadIdx.x >> 6);
    int lane = threadIdx.x & 63;
    if (row >= N) return;
    short8v zv = ((const short8v*)(Z + (size_t)row * HH))[lane];
    float v[8];
    float sum = 0.f, sum2 = 0.f;
#pragma unroll
    for (int q = 0; q < 8; ++q) {
        float t = tanhf(bf2f(zv[q]));
        v[q] = t; sum += t; sum2 = fmaf(t, t, sum2);
    }
#pragma unroll
    for (int m = 32; m >= 1; m >>= 1) {
        sum += __shfl_xor(sum, m); sum2 += __shfl_xor(sum2, m);
    }
    float mu = sum * (1.f/HH);
    float rs = rsqrtf(sum2 * (1.f/HH) - mu*mu + 1e-5f);
    {
        const float4* gp = (const float4*)g1 + lane * 2;
        const float4* bp = (const float4*)b1 + lane * 2;
        float4 g0 = gp[0], g1v = gp[1], c0 = bp[0], c1 = bp[1];
        float gg[8] = {g0.x, g0.y, g0.z, g0.w, g1v.x, g1v.y, g1v.z, g1v.w};
        float cc[8] = {c0.x, c0.y, c0.z, c0.w, c1.x, c1.y, c1.z, c1.w};
        const float4* sp = (const float4*)(sc + (size_t)row * HH) + lane * 2;
        float4 s0 = sp[0], s1 = sp[1];
        float ssv[8] = {s0.x, s0.y, s0.z, s0.w, s1.x, s1.y, s1.z, s1.w};
        sum = 0.f; sum2 = 0.f;
#pragma unroll
        for (int q = 0; q < 8; ++q) {
            float x2 = (v[q]-mu)*rs*gg[q] + cc[q];
            float t = tanhf(ssv[q] + x2);
            v[q] = t; sum += t; sum2 = fmaf(t, t, sum2);
        }
    }
#pragma unroll
    for (int m = 32; m >= 1; m >>= 1) {
        sum += __shfl_xor(sum, m); sum2 += __shfl_xor(sum2, m);
    }
    mu = sum * (1.f/HH);
    rs = rsqrtf(sum2 * (1.f/HH) - mu*mu + 1e-5f);
    const float4* gp = (const float4*)g2 + lane * 2;
    const float4* bp = (const float4*)b2 + lane * 2;
    float4 g0 = gp[0], g1v = gp[1], c0 = bp[0], c1 = bp[1];
    float gg[8] = {g0.x, g0.y, g0.z, g0.w, g1v.x, g1v.y, g1v.z, g1v.w};
    float cc[8] = {c0.x, c0.y, c0.z, c0.w, c1.x, c1.y, c1.z, c1.w};
    float o[8];
#pragma unroll
    for (int q = 0; q < 8; ++q) o[q] = (v[q]-mu)*rs*gg[q] + cc[q];
    if (outB) {
        short8v ob;
#pragma unroll
        for (int q = 0; q < 8; ++q) ob[q] = f2bf(o[q]);
        ((short8v*)(outB + (size_t)row * HH))[lane] = ob;
    }
    if (outF) {
        float4* op = (float4*)(outF + (size_t)row * HH) + lane * 2;
        op[0] = make_float4(o[0], o[1], o[2], o[3]);
        op[1] = make_float4(o[4], o[5], o[6], o[7]);
    }
    if (cWp) {
        const float4* wp = (const float4*)cWp + lane * 2;
        float4 w0 = wp[0], w1 = wp[1];
        float acc = o[0]*w0.x + o[1]*w0.y + o[2]*w0.z + o[3]*w0.w
                  + o[4]*w1.x + o[5]*w1.y + o[6]*w1.z + o[7]*w1.w;
#pragma unroll
        for (int m = 32; m >= 1; m >>= 1) acc += __shfl_xor(acc, m);
        if (lane == 0) outCls[row] = 1.f / (1.f + expf(-(acc + cbp[0])));
    }
}

extern "C" void kernel_launch(void* const* d_in, const int* in_sizes, int n_in,
                              void* d_out, int out_size, void* d_ws, size_t ws_size,
                              hipStream_t stream)
{
    (void)in_sizes; (void)n_in; (void)out_size; (void)ws_size;
    const int N = NN, E = NE, H = HH;
    const size_t NHf = (size_t)N * H;

    const float* fu0 = (const float*)d_in[0];
    const float* fi1 = (const float*)d_in[3];
    const float* fu2 = (const float*)d_in[4];
    const int* eUI0 = (const int*)d_in[6];
    const int* eIU1 = (const int*)d_in[9];
    const float* Wu  = (const float*)d_in[10];
    const float* bu  = (const float*)d_in[11];
    const float* Wi  = (const float*)d_in[12];
    const float* bi  = (const float*)d_in[13];
    const float* gfW = (const float*)d_in[14];
    const float* gfb = (const float*)d_in[15];
    const float* gaw = (const float*)d_in[16];
    const float* gab = (const float*)d_in[17];
    const float* gbias = (const float*)d_in[18];
    const float* prW = (const float*)d_in[19];
    const float* prb = (const float*)d_in[20];
    const float* dW  = (const float*)d_in[21];
    const float* db  = (const float*)d_in[22];
    const float* dlg = (const float*)d_in[23];
    const float* dlb = (const float*)d_in[24];
    const float* rlg = (const float*)d_in[25];
    const float* rlb = (const float*)d_in[26];
    const float* cW  = (const float*)d_in[27];
    const float* cb  = (const float*)d_in[28];

    // fp32 region
    float* B5     = (float*)d_ws;      // residual sc (fp32)
    float* ssb    = B5 + NHf;          // [N]
    float* tsb    = ssb + N;           // [N]
    float* uvall  = tsb + N;           // [2048]
    float* s0t0a  = uvall + 2048;      // [8]
    float* wvb    = s0t0a + 8;         // [E]
    int* counts0 = (int*)(wvb + E);
    int* counts1 = counts0 + N;
    int* offs0   = counts1 + N;
    int* offs1   = offs0 + N + 1;
    int* cur0    = offs1 + N + 1;
    int* cur1    = cur0 + N;
    int* tvals   = cur1 + N;           // [E]
    int* eidxb   = tvals + E;          // [E]
    size_t boff = (size_t)((char*)(eidxb + E) - (char*)d_ws);
    boff = (boff + 15) & ~(size_t)15;
    short* S0    = (short*)((char*)d_ws + boff); // [2*NHf]: fu2, fu0 bf16
    short* SUHU  = S0 + 2 * NHf;                 // [2*NHf]: su, hu0
    short* XI1   = SUHU + 2 * NHf;
    short* HI    = XI1 + NHf / 2;
    short* SINEW = HI + NHf;
    short* T4    = SINEW + NHf;
    short* SUF   = T4 + NHf;
    short* WTu   = SUF + NHf;
    short* WTi   = WTu + 512 * 512;
    short* WTg0  = WTi + 512 * 256;
    short* WTg1  = WTg0 + 512 * 512;
    short* WTpr  = WTg1 + 512 * 512;
    short* WTd   = WTpr + 512 * 512;
    short* SU  = SUHU;
    short* HU0 = SUHU + NHf;
    short* XB  = SINEW;
    short* ZB  = SU;

    // ---- batched pre-passes ----
    hipLaunchKernelGGL(wtr_all, dim3(16, 16, 9), dim3(32, 8), 0, stream,
                       Wu, Wi, gfW, prW, dW, WTu, WTi, WTg0, WTg1, WTpr, WTd);
    int nh8 = (int)(NHf / 8);
    int ftot = 2 * nh8 + nh8 / 2;
    hipLaunchKernelGGL(f2b_all, dim3((ftot + 255) / 256), dim3(256), 0, stream,
                       fu2, fu0, fi1, S0, XI1, nh8);
    hipMemsetAsync(counts0, 0, 2 * N * sizeof(int), stream);
    hipLaunchKernelGGL(count2_kernel, dim3((2 * E + 255) / 256), dim3(256), 0, stream,
                       eUI0, eIU1, counts0, counts1, E);
    hipLaunchKernelGGL(scan2_kernel, dim3(2), dim3(1024), 0, stream,
                       counts0, counts1, offs0, offs1, cur0, cur1, N);
    hipLaunchKernelGGL(gat_pre2, dim3(130, 2), dim3(256), 0, stream,
                       gfW, gfb, gaw, uvall, s0t0a);

    const int rgrid = (N + 3) / 4;
    const int egrid = (E + 255) / 256;
    auto MLIN = [&](const short* X, const short* WT, const float* b,
                    float* oF, short* oB, int M, int K,
                    const short* rdH, const short* rdT, const float* rduv,
                    const float* rds0) {
        int nwg = ((M + 127) / 128) * 4;
        int grid = nwg + (rdH ? rgrid : 0);
        hipLaunchKernelGGL(mfma_lin, dim3(grid), dim3(256), 0, stream,
                           X, WT, b, oF, oB, M, K,
                           rdH, rdT, rduv, rds0, ssb, tsb, N);
    };

    auto GAT = [&](int r, const short* headB, const short* tailB, const short* WTg,
                   const int* edges, int* offs, int* curs, short* outB) {
        MLIN(tailB, WTg, gfb + r * H, nullptr, T4, N, 512,
             headB, tailB, uvall + r * 1024, s0t0a + r * 4);
        hipLaunchKernelGGL(fill_kernel, dim3(egrid), dim3(256), 0, stream,
                           edges, edges + E, ssb, tsb, gab + r, curs, tvals, wvb,
                           eidxb, E);
        hipLaunchKernelGGL(sortbkt_kernel, dim3(rgrid), dim3(256), 0, stream,
                           offs, tvals, wvb, eidxb, N);
        hipLaunchKernelGGL(gat_agg_kernel, dim3(rgrid), dim3(256), 0, stream,
                           offs, tvals, wvb, T4, headB, gbias + (size_t)r * H, outB, N);
    };

    // input transforms (su & hu0 batched)
    MLIN(S0, WTu, bu, nullptr, SUHU, 2 * N, 512, nullptr, nullptr, nullptr, nullptr);
    MLIN(XI1, WTi, bi, nullptr, HI, N, 256, nullptr, nullptr, nullptr, nullptr);
    GAT(1, HI, SU, WTg1, eIU1, offs1, cur1, SINEW);
    GAT(0, HU0, SINEW, WTg0, eUI0, offs0, cur0, SUF);

    // Res_DNN head
    MLIN(SUF, WTpr, prb, B5, XB, N, 512, nullptr, nullptr, nullptr, nullptr);
    for (int r = 0; r < 2; ++r) {
        MLIN(XB, WTd + (size_t)(r * 2) * 512 * 512, db + (r * 2) * H,
             nullptr, ZB, N, 512, nullptr, nullptr, nullptr, nullptr);
        hipLaunchKernelGGL(tanh_ln_kernel, dim3(rgrid), dim3(256), 0, stream,
                           ZB, dlg + (r * 2) * H, dlb + (r * 2) * H, XB, N);
        MLIN(XB, WTd + (size_t)(r * 2 + 1) * 512 * 512, db + (r * 2 + 1) * H,
             nullptr, ZB, N, 512, nullptr, nullptr, nullptr, nullptr);
        if (r == 0) {
            hipLaunchKernelGGL(tanh_ln2_kernel, dim3(rgrid), dim3(256), 0, stream,
                               ZB, B5, dlg + H, dlb + H, rlg, rlb,
                               XB, B5, (const float*)nullptr, (const float*)nullptr,
                               (float*)nullptr, N);
        } else {
            hipLaunchKernelGGL(tanh_ln2_kernel, dim3(rgrid), dim3(256), 0, stream,
                               ZB, B5, dlg + 3 * H, dlb + 3 * H, rlg + H, rlb + H,
                               (short*)nullptr, (float*)nullptr, cW, cb,
                               (float*)d_out, N);
        }
    }
}

// Round 13
// 512.496 us; speedup vs baseline: 1.1946x; 1.0070x over previous
//
#include <hip/hip_runtime.h>
#include <math.h>

#define NN 20000
#define NE 200000
#define HH 512

typedef __attribute__((ext_vector_type(8))) short short8v;
typedef __attribute__((ext_vector_type(4))) float f32x4;

__device__ inline short f2bf(float f) {
    union { float f; unsigned u; } v; v.f = f;
    unsigned r = (v.u + 0x7fffu + ((v.u >> 16) & 1u)) >> 16;
    return (short)r;
}
__device__ inline float bf2f(short s) {
    union { unsigned u; float f; } v;
    v.u = ((unsigned)(unsigned short)s) << 16;
    return v.f;
}

__device__ inline void gload_lds16(const void* g, void* l) {
    __builtin_amdgcn_global_load_lds(
        (const __attribute__((address_space(1))) void*)g,
        (__attribute__((address_space(3))) void*)l, 16, 0, 0);
}

// ---------------- batched weight transpose+bf16 (9 weights, one launch) -----
__global__ __launch_bounds__(256)
void wtr_all(const float* __restrict__ Wu, const float* __restrict__ Wi,
             const float* __restrict__ gfW, const float* __restrict__ prW,
             const float* __restrict__ dW,
             short* __restrict__ WTu, short* __restrict__ WTi,
             short* __restrict__ WTg0, short* __restrict__ WTg1,
             short* __restrict__ WTpr, short* __restrict__ WTd)
{
    __shared__ float t[32][33];
    int z = blockIdx.z;
    const float* src; short* dst; int K;
    if (z == 0)      { src = Wu;  dst = WTu;  K = 512; }
    else if (z == 1) { src = Wi;  dst = WTi;  K = 256; }
    else if (z == 2) { src = gfW; dst = WTg0; K = 512; }
    else if (z == 3) { src = gfW + (size_t)512 * 512; dst = WTg1; K = 512; }
    else if (z == 4) { src = prW; dst = WTpr; K = 512; }
    else { src = dW + (size_t)(z - 5) * 512 * 512;
           dst = WTd + (size_t)(z - 5) * 512 * 512; K = 512; }
    int by = blockIdx.y * 32;
    if (by >= K) return;
    int bx = blockIdx.x * 32;
    int tx = threadIdx.x, ty = threadIdx.y;
    for (int i = ty; i < 32; i += 8)
        t[i][tx] = src[(size_t)(by + i) * 512 + bx + tx];
    __syncthreads();
    for (int i = ty; i < 32; i += 8)
        dst[(size_t)(bx + i) * K + by + tx] = f2bf(t[tx][i]);
}

// ---------------- MFMA GEMM (128x128, BK=64, 2-stage counted vmcnt) ---------
// bf16 A; + optional rowdot tail blocks (id >= gemm grid).
__global__ __launch_bounds__(256)
void mfma_lin(const short* __restrict__ X, const short* __restrict__ WT,
              const float* __restrict__ bias, float* __restrict__ outF,
              short* __restrict__ outB, int M, int K,
              const short* __restrict__ rdH, const short* __restrict__ rdT,
              const float* __restrict__ rduv, const float* __restrict__ rds0,
              float* __restrict__ rdss, float* __restrict__ rdts, int rdN)
{
    __shared__ short8v pool[4096];   // 64 KB

    const int tid = threadIdx.x;
    const int lane = tid & 63;
    const int w = tid >> 6;

    const int nby = (M + 127) >> 7;
    const int nwg = nby << 2;
    int id = blockIdx.x;

    if (id >= nwg) {                 // ---------- rowdot role ----------
        int row = (id - nwg) * 4 + w;
        if (row >= rdN) return;
        short8v h = ((const short8v*)(rdH + (size_t)row * HH))[lane];
        short8v t = ((const short8v*)(rdT + (size_t)row * HH))[lane];
        const float4* up = (const float4*)rduv + lane * 2;
        const float4* vp = (const float4*)(rduv + HH) + lane * 2;
        float4 u0 = up[0], u1 = up[1], v0 = vp[0], v1 = vp[1];
        float a = bf2f(h[0])*u0.x + bf2f(h[1])*u0.y + bf2f(h[2])*u0.z + bf2f(h[3])*u0.w
                + bf2f(h[4])*u1.x + bf2f(h[5])*u1.y + bf2f(h[6])*u1.z + bf2f(h[7])*u1.w;
        float b = bf2f(t[0])*v0.x + bf2f(t[1])*v0.y + bf2f(t[2])*v0.z + bf2f(t[3])*v0.w
                + bf2f(t[4])*v1.x + bf2f(t[5])*v1.y + bf2f(t[6])*v1.z + bf2f(t[7])*v1.w;
#pragma unroll
        for (int m = 32; m >= 1; m >>= 1) {
            a += __shfl_xor(a, m);
            b += __shfl_xor(b, m);
        }
        if (lane == 0) { rdss[row] = a + rds0[0]; rdts[row] = b + rds0[1]; }
        return;
    }

    // ---------- GEMM role ----------
    const int q = nwg >> 3, r = nwg & 7;
    int xcd = id & 7, wi = id >> 3;
    int wgid = (xcd < r ? xcd * (q + 1) : r * (q + 1) + (xcd - r) * q) + wi;
    const int col0 = (wgid & 3) * 128;
    const int row0 = (wgid >> 2) * 128;

    const int wr = (w >> 1) * 64;
    const int wc = (w & 1) * 64;

    const short* gsrc[8];
#pragma unroll
    for (int g = 0; g < 8; ++g) {
        int p = w * 512 + g * 64 + lane;
        if (p < 1024) {
            int row = p >> 3;
            int c = (p & 7) ^ (row & 7);
            int ga = row0 + row; if (ga >= M) ga = M - 1;
            gsrc[g] = X + (size_t)ga * K + c * 8;
        } else {
            int qq = p - 1024;
            int col = qq >> 3;
            int c = (qq & 7) ^ (col & 7);
            gsrc[g] = WT + (size_t)(col0 + col) * K + c * 8;
        }
    }

    int ar[2][4], br[2][4];
#pragma unroll
    for (int kk = 0; kk < 2; ++kk) {
#pragma unroll
        for (int i = 0; i < 4; ++i) {
            int rr = wr + i * 16 + (lane & 15);
            ar[kk][i] = rr * 8 + ((kk * 4 + (lane >> 4)) ^ (rr & 7));
            int nn = wc + i * 16 + (lane & 15);
            br[kk][i] = 1024 + nn * 8 + ((kk * 4 + (lane >> 4)) ^ (nn & 7));
        }
    }

    f32x4 acc[4][4];
#pragma unroll
    for (int i = 0; i < 4; ++i)
#pragma unroll
        for (int j = 0; j < 4; ++j)
            acc[i][j] = (f32x4){0.f, 0.f, 0.f, 0.f};

    auto stage = [&](int buf, int kk) {
        short8v* base = pool + buf * 2048 + w * 512;
#pragma unroll
        for (int g = 0; g < 8; ++g)
            gload_lds16(gsrc[g] + kk, base + g * 64);
    };

    const int nt = K >> 6;
    stage(0, 0);
    if (nt > 1) stage(1, 64);
    int cur = 0;
    for (int t = 0; t < nt; ++t) {
        if (t + 1 < nt) asm volatile("s_waitcnt vmcnt(8)" ::: "memory");
        else            asm volatile("s_waitcnt vmcnt(0)" ::: "memory");
        __builtin_amdgcn_s_barrier();
        const short8v* S = pool + cur * 2048;
#pragma unroll
        for (int kk = 0; kk < 2; ++kk) {
            short8v af[4], bf[4];
#pragma unroll
            for (int i = 0; i < 4; ++i) af[i] = S[ar[kk][i]];
#pragma unroll
            for (int j = 0; j < 4; ++j) bf[j] = S[br[kk][j]];
#pragma unroll
            for (int i = 0; i < 4; ++i)
#pragma unroll
                for (int j = 0; j < 4; ++j)
                    acc[i][j] = __builtin_amdgcn_mfma_f32_16x16x32_bf16(af[i], bf[j], acc[i][j], 0, 0, 0);
        }
        __builtin_amdgcn_s_barrier();
        if (t + 2 < nt) stage(cur, (t + 2) * 64);
        cur ^= 1;
    }

    float bj[4];
#pragma unroll
    for (int j = 0; j < 4; ++j)
        bj[j] = bias[col0 + wc + j * 16 + (lane & 15)];

    if (outF) {
#pragma unroll
        for (int i = 0; i < 4; ++i) {
#pragma unroll
            for (int rr = 0; rr < 4; ++rr) {
                int row = row0 + wr + i * 16 + (lane >> 4) * 4 + rr;
                if (row < M) {
                    float* op = outF + (size_t)row * HH + col0 + wc + (lane & 15);
#pragma unroll
                    for (int j = 0; j < 4; ++j) op[j * 16] = acc[i][j][rr] + bj[j];
                }
            }
        }
    }
    if (outB) {   // block-cooperative bf16 epilogue, padded stride 136
        short* lt = (short*)pool;    // [128][136] bf16 = 34 KB
#pragma unroll
        for (int i = 0; i < 4; ++i)
#pragma unroll
            for (int rr = 0; rr < 4; ++rr) {
                int lrow = wr + i * 16 + (lane >> 4) * 4 + rr;
#pragma unroll
                for (int j = 0; j < 4; ++j)
                    lt[lrow * 136 + wc + j * 16 + (lane & 15)] = f2bf(acc[i][j][rr] + bj[j]);
            }
        __syncthreads();
#pragma unroll
        for (int k = 0; k < 8; ++k) {
            int row = (tid >> 4) + 16 * k;
            int seg = tid & 15;
            int grow = row0 + row;
            if (grow < M) {
                short8v vv = *(short8v*)(lt + row * 136 + seg * 8);
                *(short8v*)(outB + (size_t)grow * HH + col0 + seg * 8) = vv;
            }
        }
    }
}

// ---------------- MFMA GEMM, fp32-A variant (128x128, BK=32, 2-stage) -------
// A staged as fp32 via global_load_lds, converted to bf16 at fragment read.
// Dual A-source: rows < NA from XA, rows >= NA from XB2.
__global__ __launch_bounds__(256)
void mfma_linf(const float* __restrict__ XA, const float* __restrict__ XB2,
               int NA, const short* __restrict__ WT,
               const float* __restrict__ bias, short* __restrict__ outB,
               int M, int K)
{
    __shared__ short8v pool[3072];   // 2 stages x (1024 A-f32 + 512 B) = 48 KB

    const int tid = threadIdx.x;
    const int lane = tid & 63;
    const int w = tid >> 6;

    const int nby = (M + 127) >> 7;
    const int nwg = nby << 2;
    const int q = nwg >> 3, r = nwg & 7;
    int id = blockIdx.x;
    int xcd = id & 7, wi = id >> 3;
    int wgid = (xcd < r ? xcd * (q + 1) : r * (q + 1) + (xcd - r) * q) + wi;
    const int col0 = (wgid & 3) * 128;
    const int row0 = (wgid >> 2) * 128;

    const int wr = (w >> 1) * 64;
    const int wc = (w & 1) * 64;
    const int kg = lane >> 4;

    // staging: 4 A slots (f32x4) + 2 B slots (bf16x8) per thread
    const float* ga_[4];
#pragma unroll
    for (int g = 0; g < 4; ++g) {
        int p = w * 256 + g * 64 + lane;       // A slot in [0,1024)
        int row = p >> 3;
        int c = (p & 7) ^ (row & 7);           // pre-swizzled source chunk
        int ga = row0 + row; if (ga >= M) ga = M - 1;
        const float* base = (ga < NA) ? XA + (size_t)ga * K
                                      : XB2 + (size_t)(ga - NA) * K;
        ga_[g] = base + c * 4;
    }
    const short* gb_[2];
#pragma unroll
    for (int g = 0; g < 2; ++g) {
        int p = w * 128 + g * 64 + lane;       // B slot in [0,512)
        int col = p >> 2;
        int c = (p & 3) ^ ((col >> 1) & 3);
        gb_[g] = WT + (size_t)(col0 + col) * K + c * 8;
    }

    int arow[4], br_[4];
#pragma unroll
    for (int i = 0; i < 4; ++i) arow[i] = wr + i * 16 + (lane & 15);
#pragma unroll
    for (int j = 0; j < 4; ++j) {
        int nn = wc + j * 16 + (lane & 15);
        br_[j] = 1024 + nn * 4 + (kg ^ ((nn >> 1) & 3));
    }

    f32x4 acc[4][4];
#pragma unroll
    for (int i = 0; i < 4; ++i)
#pragma unroll
        for (int j = 0; j < 4; ++j)
            acc[i][j] = (f32x4){0.f, 0.f, 0.f, 0.f};

    auto stage = [&](int buf, int t) {
        short8v* base = pool + buf * 1536 + w * 256;
#pragma unroll
        for (int g = 0; g < 4; ++g)
            gload_lds16(ga_[g] + t * 32, base + g * 64);
        short8v* bb = pool + buf * 1536 + 1024 + w * 128;
#pragma unroll
        for (int g = 0; g < 2; ++g)
            gload_lds16(gb_[g] + t * 32, bb + g * 64);
    };

    const int nt = K >> 5;            // 16 (K=512) or 8 (K=256)
    stage(0, 0);
    if (nt > 1) stage(1, 1);
    int cur = 0;
    for (int t = 0; t < nt; ++t) {
        if (t + 1 < nt) asm volatile("s_waitcnt vmcnt(6)" ::: "memory");
        else            asm volatile("s_waitcnt vmcnt(0)" ::: "memory");
        __builtin_amdgcn_s_barrier();
        const float4* Af = (const float4*)(pool + cur * 1536);
        const short8v* S = pool + cur * 1536;
        short8v af[4], bf[4];
#pragma unroll
        for (int i = 0; i < 4; ++i) {
            int rr = arow[i];
            int s = rr & 7;
            float4 lo = Af[rr * 8 + ((2 * kg)     ^ s)];
            float4 hi = Af[rr * 8 + ((2 * kg + 1) ^ s)];
            af[i][0] = f2bf(lo.x); af[i][1] = f2bf(lo.y);
            af[i][2] = f2bf(lo.z); af[i][3] = f2bf(lo.w);
            af[i][4] = f2bf(hi.x); af[i][5] = f2bf(hi.y);
            af[i][6] = f2bf(hi.z); af[i][7] = f2bf(hi.w);
        }
#pragma unroll
        for (int j = 0; j < 4; ++j) bf[j] = S[br_[j]];
#pragma unroll
        for (int i = 0; i < 4; ++i)
#pragma unroll
            for (int j = 0; j < 4; ++j)
                acc[i][j] = __builtin_amdgcn_mfma_f32_16x16x32_bf16(af[i], bf[j], acc[i][j], 0, 0, 0);
        __builtin_amdgcn_s_barrier();
        if (t + 2 < nt) stage(cur, t + 2);
        cur ^= 1;
    }

    float bj[4];
#pragma unroll
    for (int j = 0; j < 4; ++j)
        bj[j] = bias[col0 + wc + j * 16 + (lane & 15)];

    // block-cooperative bf16 epilogue (padded stride 136; 34 KB < 48 KB pool)
    short* lt = (short*)pool;
#pragma unroll
    for (int i = 0; i < 4; ++i)
#pragma unroll
        for (int rr = 0; rr < 4; ++rr) {
            int lrow = wr + i * 16 + (lane >> 4) * 4 + rr;
#pragma unroll
            for (int j = 0; j < 4; ++j)
                lt[lrow * 136 + wc + j * 16 + (lane & 15)] = f2bf(acc[i][j][rr] + bj[j]);
        }
    __syncthreads();
#pragma unroll
    for (int k = 0; k < 8; ++k) {
        int row = (tid >> 4) + 16 * k;
        int seg = tid & 15;
        int grow = row0 + row;
        if (grow < M) {
            short8v vv = *(short8v*)(lt + row * 136 + seg * 8);
            *(short8v*)(outB + (size_t)grow * HH + col0 + seg * 8) = vv;
        }
    }
}

// ---------------- gat_pre for BOTH relations (one launch) -------------------
__global__ __launch_bounds__(256)
void gat_pre2(const float* __restrict__ gfW, const float* __restrict__ gfb,
              const float* __restrict__ gaw, float* __restrict__ uvall,
              float* __restrict__ s0t0all)
{
    int rrel = blockIdx.y;
    const float* fW = gfW + (size_t)rrel * HH * HH;
    const float* fb = gfb + rrel * HH;
    const float* aw = gaw + (size_t)rrel * 2 * HH;
    float* uv = uvall + rrel * 1024;
    float* s0t0 = s0t0all + rrel * 4;
    int row = blockIdx.x * 4 + (threadIdx.x >> 6);
    int lane = threadIdx.x & 63;
    const float4* ah = (const float4*)aw;
    const float4* at = (const float4*)(aw + HH);
    const float4* fp;
    if (row < 512)       fp = (const float4*)(fW + (size_t)row * HH);
    else if (row == 512) fp = (const float4*)fb;
    else return;
    float du = 0.f, dv = 0.f;
#pragma unroll
    for (int l = 0; l < 2; ++l) {
        int idx = lane * 2 + l;
        float4 f = fp[idx], a = ah[idx], b = at[idx];
        du += f.x*a.x + f.y*a.y + f.z*a.z + f.w*a.w;
        dv += f.x*b.x + f.y*b.y + f.z*b.z + f.w*b.w;
    }
#pragma unroll
    for (int m = 32; m >= 1; m >>= 1) {
        du += __shfl_xor(du, m);
        dv += __shfl_xor(dv, m);
    }
    if (lane == 0) {
        if (row < 512) { uv[row] = du; uv[512 + row] = dv; }
        else           { s0t0[0] = du; s0t0[1] = dv; }
    }
}

// ---------------- CSR build ----------------
__global__ __launch_bounds__(256)
void count2_kernel(const int* __restrict__ s0, const int* __restrict__ s1,
                   int* __restrict__ c0, int* __restrict__ c1, int E)
{
    int i = blockIdx.x * blockDim.x + threadIdx.x;
    if (i < E) atomicAdd(&c0[s0[i]], 1);
    else if (i < 2 * E) atomicAdd(&c1[s1[i - E]], 1);
}

__global__ __launch_bounds__(1024)
void scan2_kernel(const int* __restrict__ c0, const int* __restrict__ c1,
                  int* __restrict__ o0, int* __restrict__ o1,
                  int* __restrict__ u0, int* __restrict__ u1, int n)
{
    const int* counts = blockIdx.x ? c1 : c0;
    int* offs = blockIdx.x ? o1 : o0;
    int* curs = blockIdx.x ? u1 : u0;
    __shared__ int part[1024];
    const int tid = threadIdx.x;
    const int CH = (n + 1023) / 1024;
    const int base = tid * CH;
    int s = 0;
    for (int i = 0; i < CH; ++i) {
        int idx = base + i;
        if (idx < n) s += counts[idx];
    }
    part[tid] = s;
    __syncthreads();
    for (int d = 1; d < 1024; d <<= 1) {
        int v = 0;
        if (tid >= d) v = part[tid - d];
        __syncthreads();
        if (tid >= d) part[tid] += v;
        __syncthreads();
    }
    int run = (tid == 0) ? 0 : part[tid - 1];
    for (int i = 0; i < CH; ++i) {
        int idx = base + i;
        if (idx < n) { offs[idx] = run; curs[idx] = run; run += counts[idx]; }
    }
    if (tid == 1023) offs[n] = run;
}

// fill CSR: target ids, edge weights, original edge index (for canonical sort)
__global__ __launch_bounds__(256)
void fill_kernel(const int* __restrict__ src, const int* __restrict__ tgt,
                 const float* __restrict__ ss, const float* __restrict__ ts,
                 const float* __restrict__ ab_ptr, int* __restrict__ cursor,
                 int* __restrict__ tvals, float* __restrict__ wv,
                 int* __restrict__ eidx, int E)
{
    int i = blockIdx.x * blockDim.x + threadIdx.x;
    if (i >= E) return;
    int s = src[i], t = tgt[i];
    int pos = atomicAdd(&cursor[s], 1);
    tvals[pos] = t;
    wv[pos] = expf(tanhf(ss[s] + ts[t] + ab_ptr[0]));
    eidx[pos] = i;
}

// ---------------- canonical bucket sort (determinism) -----------------------
__global__ __launch_bounds__(256)
void sortbkt_kernel(const int* __restrict__ offs, int* __restrict__ tvals,
                    float* __restrict__ wv, const int* __restrict__ eidx, int N)
{
    __shared__ int   lt[4][512];
    __shared__ float lw[4][512];
    int w = threadIdx.x >> 6, lane = threadIdx.x & 63;
    int s = blockIdx.x * 4 + w;
    if (s >= N) return;
    int beg = offs[s], end = offs[s + 1];
    int L = end - beg;
    if (L <= 1) return;
    if (L <= 64) {
        int e = 0x7fffffff, t = 0; float fw = 0.f;
        if (lane < L) { e = eidx[beg + lane]; t = tvals[beg + lane]; fw = wv[beg + lane]; }
        int r = 0;
        for (int k = 0; k < L; ++k) {
            int ek = __shfl(e, k);
            r += (ek < e) ? 1 : 0;
        }
        if (lane < L) { tvals[beg + r] = t; wv[beg + r] = fw; }
    } else if (L <= 512) {
        for (int j = lane; j < L; j += 64) { lt[w][j] = tvals[beg + j]; lw[w][j] = wv[beg + j]; }
        asm volatile("s_waitcnt lgkmcnt(0) vmcnt(0)" ::: "memory");
        for (int j = lane; j < L; j += 64) {
            int e = eidx[beg + j];
            int r = 0;
            for (int k = 0; k < L; ++k) r += (eidx[beg + k] < e) ? 1 : 0;
            tvals[beg + r] = lt[w][j]; wv[beg + r] = lw[w][j];
        }
    }
}

// ---------------- fused GAT aggregate + combine (bf16 rows) -----------------
__global__ __launch_bounds__(256)
void gat_agg_kernel(const int* __restrict__ offs, const int* __restrict__ tvals,
                    const float* __restrict__ wv, const short* __restrict__ T,
                    const short* __restrict__ head, const float* __restrict__ gbias,
                    short* __restrict__ out, int N)
{
    int s = blockIdx.x * 4 + (threadIdx.x >> 6);
    int lane = threadIdx.x & 63;
    if (s >= N) return;
    const int beg = offs[s], end = offs[s + 1];
    float a[8];
#pragma unroll
    for (int q = 0; q < 8; ++q) a[q] = 0.f;
    float den = 0.f;

    int j = beg;
    for (; j + 4 <= end; j += 4) {
        int t0 = tvals[j], t1 = tvals[j + 1], t2 = tvals[j + 2], t3 = tvals[j + 3];
        float w0 = wv[j], w1 = wv[j + 1], w2 = wv[j + 2], w3 = wv[j + 3];
        short8v v0 = ((const short8v*)(T + (size_t)t0 * HH))[lane];
        short8v v1 = ((const short8v*)(T + (size_t)t1 * HH))[lane];
        short8v v2 = ((const short8v*)(T + (size_t)t2 * HH))[lane];
        short8v v3 = ((const short8v*)(T + (size_t)t3 * HH))[lane];
        den += w0 + w1 + w2 + w3;
#pragma unroll
        for (int q = 0; q < 8; ++q) {
            float acc = a[q];
            acc = fmaf(w0, bf2f(v0[q]), acc);
            acc = fmaf(w1, bf2f(v1[q]), acc);
            acc = fmaf(w2, bf2f(v2[q]), acc);
            acc = fmaf(w3, bf2f(v3[q]), acc);
            a[q] = acc;
        }
    }
    for (; j < end; ++j) {
        int t = tvals[j];
        float w = wv[j];
        short8v tv = ((const short8v*)(T + (size_t)t * HH))[lane];
        den += w;
#pragma unroll
        for (int q = 0; q < 8; ++q) a[q] = fmaf(w, bf2f(tv[q]), a[q]);
    }
    float inv = (den > 0.f) ? 1.f / den : 0.f;

    short8v h = ((const short8v*)(head + (size_t)s * HH))[lane];
    const float4* bp = (const float4*)gbias + lane * 2;
    float4 b0 = bp[0], b1 = bp[1];
    float bb[8] = {b0.x, b0.y, b0.z, b0.w, b1.x, b1.y, b1.z, b1.w};
    short8v o;
#pragma unroll
    for (int q = 0; q < 8; ++q)
        o[q] = f2bf((bf2f(h[q]) + a[q] * inv + bb[q]) * 0.5f);
    ((short8v*)(out + (size_t)s * HH))[lane] = o;
}

// ---------------- single tanh+LN (d=0 layers) -------------------------------
__global__ __launch_bounds__(256)
void tanh_ln_kernel(const short* __restrict__ Z,
                    const float* __restrict__ g, const float* __restrict__ bta,
                    short* __restrict__ outB, int N)
{
    int row = blockIdx.x * 4 + (threadIdx.x >> 6);
    int lane = threadIdx.x & 63;
    if (row >= N) return;
    short8v zv = ((const short8v*)(Z + (size_t)row * HH))[lane];
    float v[8];
    float sum = 0.f, sum2 = 0.f;
#pragma unroll
    for (int q = 0; q < 8; ++q) {
        float t = tanhf(bf2f(zv[q]));
        v[q] = t; sum += t; sum2 = fmaf(t, t, sum2);
    }
#pragma unroll
    for (int m = 32; m >= 1; m >>= 1) {
        sum += __shfl_xor(sum, m); sum2 += __shfl_xor(sum2, m);
    }
    float mu = sum * (1.f/HH);
    float rs = rsqrtf(sum2 * (1.f/HH) - mu*mu + 1e-5f);
    const float4* gp = (const float4*)g + lane * 2;
    const float4* bp = (const float4*)bta + lane * 2;
    float4 g0 = gp[0], g1 = gp[1], c0 = bp[0], c1 = bp[1];
    float gg[8] = {g0.x, g0.y, g0.z, g0.w, g1.x, g1.y, g1.z, g1.w};
    float cc[8] = {c0.x, c0.y, c0.z, c0.w, c1.x, c1.y, c1.z, c1.w};
    short8v ob;
#pragma unroll
    for (int q = 0; q < 8; ++q) ob[q] = f2bf((v[q]-mu)*rs*gg[q] + cc[q]);
    ((short8v*)(outB + (size_t)row * HH))[lane] = ob;
}

// ---------------- fused double LN (d=1 + residual) --------------------------
__global__ __launch_bounds__(256)
void tanh_ln2_kernel(const short* __restrict__ Z, const float* __restrict__ sc,
                     const float* __restrict__ g1, const float* __restrict__ b1,
                     const float* __restrict__ g2, const float* __restrict__ b2,
                     short* __restrict__ outB, float* __restrict__ outF,
                     const float* __restrict__ cWp, const float* __restrict__ cbp,
                     float* __restrict__ outCls, int N)
{
    int row = blockIdx.x * 4 + (threadIdx.x >> 6);
    int lane = threadIdx.x & 63;
    if (row >= N) return;
    short8v zv = ((const short8v*)(Z + (size_t)row * HH))[lane];
    float v[8];
    float sum = 0.f, sum2 = 0.f;
#pragma unroll
    for (int q = 0; q < 8; ++q) {
        float t = tanhf(bf2f(zv[q]));
        v[q] = t; sum += t; sum2 = fmaf(t, t, sum2);
    }
#pragma unroll
    for (int m = 32; m >= 1; m >>= 1) {
        sum += __shfl_xor(sum, m); sum2 += __shfl_xor(sum2, m);
    }
    float mu = sum * (1.f/HH);
    float rs = rsqrtf(sum2 * (1.f/HH) - mu*mu + 1e-5f);
    {
        const float4* gp = (const float4*)g1 + lane * 2;
        const float4* bp = (const float4*)b1 + lane * 2;
        float4 g0 = gp[0], g1v = gp[1], c0 = bp[0], c1 = bp[1];
        float gg[8] = {g0.x, g0.y, g0.z, g0.w, g1v.x, g1v.y, g1v.z, g1v.w};
        float cc[8] = {c0.x, c0.y, c0.z, c0.w, c1.x, c1.y, c1.z, c1.w};
        const float4* sp = (const float4*)(sc + (size_t)row * HH) + lane * 2;
        float4 s0 = sp[0], s1 = sp[1];
        float ssv[8] = {s0.x, s0.y, s0.z, s0.w, s1.x, s1.y, s1.z, s1.w};
        sum = 0.f; sum2 = 0.f;
#pragma unroll
        for (int q = 0; q < 8; ++q) {
            float x2 = (v[q]-mu)*rs*gg[q] + cc[q];
            float t = tanhf(ssv[q] + x2);
            v[q] = t; sum += t; sum2 = fmaf(t, t, sum2);
        }
    }
#pragma unroll
    for (int m = 32; m >= 1; m >>= 1) {
        sum += __shfl_xor(sum, m); sum2 += __shfl_xor(sum2, m);
    }
    mu = sum * (1.f/HH);
    rs = rsqrtf(sum2 * (1.f/HH) - mu*mu + 1e-5f);
    const float4* gp = (const float4*)g2 + lane * 2;
    const float4* bp = (const float4*)b2 + lane * 2;
    float4 g0 = gp[0], g1v = gp[1], c0 = bp[0], c1 = bp[1];
    float gg[8] = {g0.x, g0.y, g0.z, g0.w, g1v.x, g1v.y, g1v.z, g1v.w};
    float cc[8] = {c0.x, c0.y, c0.z, c0.w, c1.x, c1.y, c1.z, c1.w};
    float o[8];
#pragma unroll
    for (int q = 0; q < 8; ++q) o[q] = (v[q]-mu)*rs*gg[q] + cc[q];
    if (outB) {
        short8v ob;
#pragma unroll
        for (int q = 0; q < 8; ++q) ob[q] = f2bf(o[q]);
        ((short8v*)(outB + (size_t)row * HH))[lane] = ob;
    }
    if (outF) {
        float4* op = (float4*)(outF + (size_t)row * HH) + lane * 2;
        op[0] = make_float4(o[0], o[1], o[2], o[3]);
        op[1] = make_float4(o[4], o[5], o[6], o[7]);
    }
    if (cWp) {
        const float4* wp = (const float4*)cWp + lane * 2;
        float4 w0 = wp[0], w1 = wp[1];
        float acc = o[0]*w0.x + o[1]*w0.y + o[2]*w0.z + o[3]*w0.w
                  + o[4]*w1.x + o[5]*w1.y + o[6]*w1.z + o[7]*w1.w;
#pragma unroll
        for (int m = 32; m >= 1; m >>= 1) acc += __shfl_xor(acc, m);
        if (lane == 0) outCls[row] = 1.f / (1.f + expf(-(acc + cbp[0])));
    }
}

extern "C" void kernel_launch(void* const* d_in, const int* in_sizes, int n_in,
                              void* d_out, int out_size, void* d_ws, size_t ws_size,
                              hipStream_t stream)
{
    (void)in_sizes; (void)n_in; (void)out_size; (void)ws_size;
    const int N = NN, E = NE, H = HH;
    const size_t NHf = (size_t)N * H;

    const float* fu0 = (const float*)d_in[0];
    const float* fi1 = (const float*)d_in[3];
    const float* fu2 = (const float*)d_in[4];
    const int* eUI0 = (const int*)d_in[6];
    const int* eIU1 = (const int*)d_in[9];
    const float* Wu  = (const float*)d_in[10];
    const float* bu  = (const float*)d_in[11];
    const float* Wi  = (const float*)d_in[12];
    const float* bi  = (const float*)d_in[13];
    const float* gfW = (const float*)d_in[14];
    const float* gfb = (const float*)d_in[15];
    const float* gaw = (const float*)d_in[16];
    const float* gab = (const float*)d_in[17];
    const float* gbias = (const float*)d_in[18];
    const float* prW = (const float*)d_in[19];
    const float* prb = (const float*)d_in[20];
    const float* dW  = (const float*)d_in[21];
    const float* db  = (const float*)d_in[22];
    const float* dlg = (const float*)d_in[23];
    const float* dlb = (const float*)d_in[24];
    const float* rlg = (const float*)d_in[25];
    const float* rlb = (const float*)d_in[26];
    const float* cW  = (const float*)d_in[27];
    const float* cb  = (const float*)d_in[28];

    // fp32 region
    float* B5     = (float*)d_ws;      // residual sc (fp32)
    float* ssb    = B5 + NHf;          // [N]
    float* tsb    = ssb + N;           // [N]
    float* uvall  = tsb + N;           // [2048]
    float* s0t0a  = uvall + 2048;      // [8]
    float* wvb    = s0t0a + 8;         // [E]
    int* counts0 = (int*)(wvb + E);
    int* counts1 = counts0 + N;
    int* offs0   = counts1 + N;
    int* offs1   = offs0 + N + 1;
    int* cur0    = offs1 + N + 1;
    int* cur1    = cur0 + N;
    int* tvals   = cur1 + N;           // [E]
    int* eidxb   = tvals + E;          // [E]
    size_t boff = (size_t)((char*)(eidxb + E) - (char*)d_ws);
    boff = (boff + 15) & ~(size_t)15;
    short* SUHU  = (short*)((char*)d_ws + boff);  // [2*NHf]: su, hu0
    short* HI    = SUHU + 2 * NHf;
    short* SINEW = HI + NHf;
    short* T4    = SINEW + NHf;
    short* SUF   = T4 + NHf;
    short* WTu   = SUF + NHf;
    short* WTi   = WTu + 512 * 512;
    short* WTg0  = WTi + 512 * 256;
    short* WTg1  = WTg0 + 512 * 512;
    short* WTpr  = WTg1 + 512 * 512;
    short* WTd   = WTpr + 512 * 512;
    short* SU  = SUHU;
    short* HU0 = SUHU + NHf;
    short* XB  = SINEW;
    short* ZB  = SU;

    // ---- batched pre-passes ----
    hipLaunchKernelGGL(wtr_all, dim3(16, 16, 9), dim3(32, 8), 0, stream,
                       Wu, Wi, gfW, prW, dW, WTu, WTi, WTg0, WTg1, WTpr, WTd);
    hipMemsetAsync(counts0, 0, 2 * N * sizeof(int), stream);
    hipLaunchKernelGGL(count2_kernel, dim3((2 * E + 255) / 256), dim3(256), 0, stream,
                       eUI0, eIU1, counts0, counts1, E);
    hipLaunchKernelGGL(scan2_kernel, dim3(2), dim3(1024), 0, stream,
                       counts0, counts1, offs0, offs1, cur0, cur1, N);
    hipLaunchKernelGGL(gat_pre2, dim3(130, 2), dim3(256), 0, stream,
                       gfW, gfb, gaw, uvall, s0t0a);

    const int rgrid = (N + 3) / 4;
    const int egrid = (E + 255) / 256;
    auto MLIN = [&](const short* X, const short* WT, const float* b,
                    float* oF, short* oB, int M, int K,
                    const short* rdH, const short* rdT, const float* rduv,
                    const float* rds0) {
        int nwg = ((M + 127) / 128) * 4;
        int grid = nwg + (rdH ? rgrid : 0);
        hipLaunchKernelGGL(mfma_lin, dim3(grid), dim3(256), 0, stream,
                           X, WT, b, oF, oB, M, K,
                           rdH, rdT, rduv, rds0, ssb, tsb, N);
    };
    auto MLINF = [&](const float* XA, const float* XB2, int NA, const short* WT,
                     const float* b, short* oB, int M, int K) {
        int nwg = ((M + 127) / 128) * 4;
        hipLaunchKernelGGL(mfma_linf, dim3(nwg), dim3(256), 0, stream,
                           XA, XB2, NA, WT, b, oB, M, K);
    };

    auto GAT = [&](int r, const short* headB, const short* tailB, const short* WTg,
                   const int* edges, int* offs, int* curs, short* outB) {
        MLIN(tailB, WTg, gfb + r * H, nullptr, T4, N, 512,
             headB, tailB, uvall + r * 1024, s0t0a + r * 4);
        hipLaunchKernelGGL(fill_kernel, dim3(egrid), dim3(256), 0, stream,
                           edges, edges + E, ssb, tsb, gab + r, curs, tvals, wvb,
                           eidxb, E);
        hipLaunchKernelGGL(sortbkt_kernel, dim3(rgrid), dim3(256), 0, stream,
                           offs, tvals, wvb, eidxb, N);
        hipLaunchKernelGGL(gat_agg_kernel, dim3(rgrid), dim3(256), 0, stream,
                           offs, tvals, wvb, T4, headB, gbias + (size_t)r * H, outB, N);
    };

    // input transforms: fp32-A GEMMs read raw features directly (no f2b pass)
    MLINF(fu2, fu0, N, WTu, bu, SUHU, 2 * N, 512);    // su + hu0
    MLINF(fi1, fi1, N, WTi, bi, HI, N, 256);          // hi
    GAT(1, HI, SU, WTg1, eIU1, offs1, cur1, SINEW);
    GAT(0, HU0, SINEW, WTg0, eUI0, offs0, cur0, SUF);

    // Res_DNN head
    MLIN(SUF, WTpr, prb, B5, XB, N, 512, nullptr, nullptr, nullptr, nullptr);
    for (int r = 0; r < 2; ++r) {
        MLIN(XB, WTd + (size_t)(r * 2) * 512 * 512, db + (r * 2) * H,
             nullptr, ZB, N, 512, nullptr, nullptr, nullptr, nullptr);
        hipLaunchKernelGGL(tanh_ln_kernel, dim3(rgrid), dim3(256), 0, stream,
                           ZB, dlg + (r * 2) * H, dlb + (r * 2) * H, XB, N);
        MLIN(XB, WTd + (size_t)(r * 2 + 1) * 512 * 512, db + (r * 2 + 1) * H,
             nullptr, ZB, N, 512, nullptr, nullptr, nullptr, nullptr);
        if (r == 0) {
            hipLaunchKernelGGL(tanh_ln2_kernel, dim3(rgrid), dim3(256), 0, stream,
                               ZB, B5, dlg + H, dlb + H, rlg, rlb,
                               XB, B5, (const float*)nullptr, (const float*)nullptr,
                               (float*)nullptr, N);
        } else {
            hipLaunchKernelGGL(tanh_ln2_kernel, dim3(rgrid), dim3(256), 0, stream,
                               ZB, B5, dlg + 3 * H, dlb + 3 * H, rlg + H, rlb + H,
                               (short*)nullptr, (float*)nullptr, cW, cb,
                               (float*)d_out, N);
        }
    }
}

// Round 14
// 506.084 us; speedup vs baseline: 1.2098x; 1.0127x over previous
//
#include <hip/hip_runtime.h>
#include <math.h>

#define NN 20000
#define NE 200000
#define HH 512

typedef __attribute__((ext_vector_type(8))) short short8v;
typedef __attribute__((ext_vector_type(4))) float f32x4;

__device__ inline short f2bf(float f) {
    union { float f; unsigned u; } v; v.f = f;
    unsigned r = (v.u + 0x7fffu + ((v.u >> 16) & 1u)) >> 16;
    return (short)r;
}
__device__ inline float bf2f(short s) {
    union { unsigned u; float f; } v;
    v.u = ((unsigned)(unsigned short)s) << 16;
    return v.f;
}

__device__ inline void gload_lds16(const void* g, void* l) {
    __builtin_amdgcn_global_load_lds(
        (const __attribute__((address_space(1))) void*)g,
        (__attribute__((address_space(3))) void*)l, 16, 0, 0);
}

// ---------------- batched weight transpose+bf16 (9 weights, one launch) -----
__global__ __launch_bounds__(256)
void wtr_all(const float* __restrict__ Wu, const float* __restrict__ Wi,
             const float* __restrict__ gfW, const float* __restrict__ prW,
             const float* __restrict__ dW,
             short* __restrict__ WTu, short* __restrict__ WTi,
             short* __restrict__ WTg0, short* __restrict__ WTg1,
             short* __restrict__ WTpr, short* __restrict__ WTd)
{
    __shared__ float t[32][33];
    int z = blockIdx.z;
    const float* src; short* dst; int K;
    if (z == 0)      { src = Wu;  dst = WTu;  K = 512; }
    else if (z == 1) { src = Wi;  dst = WTi;  K = 256; }
    else if (z == 2) { src = gfW; dst = WTg0; K = 512; }
    else if (z == 3) { src = gfW + (size_t)512 * 512; dst = WTg1; K = 512; }
    else if (z == 4) { src = prW; dst = WTpr; K = 512; }
    else { src = dW + (size_t)(z - 5) * 512 * 512;
           dst = WTd + (size_t)(z - 5) * 512 * 512; K = 512; }
    int by = blockIdx.y * 32;
    if (by >= K) return;
    int bx = blockIdx.x * 32;
    int tx = threadIdx.x, ty = threadIdx.y;
    for (int i = ty; i < 32; i += 8)
        t[i][tx] = src[(size_t)(by + i) * 512 + bx + tx];
    __syncthreads();
    for (int i = ty; i < 32; i += 8)
        dst[(size_t)(bx + i) * K + by + tx] = f2bf(t[tx][i]);
}

// ---------------- MFMA GEMM (128x128, BK=64, 2-stage counted vmcnt) ---------
// bf16 A; + optional rowdot tail blocks (id >= gemm grid).
__global__ __launch_bounds__(256)
void mfma_lin(const short* __restrict__ X, const short* __restrict__ WT,
              const float* __restrict__ bias, float* __restrict__ outF,
              short* __restrict__ outB, int M, int K,
              const short* __restrict__ rdH, const short* __restrict__ rdT,
              const float* __restrict__ rduv, const float* __restrict__ rds0,
              float* __restrict__ rdss, float* __restrict__ rdts, int rdN)
{
    __shared__ short8v pool[4096];   // 64 KB

    const int tid = threadIdx.x;
    const int lane = tid & 63;
    const int w = tid >> 6;

    const int nby = (M + 127) >> 7;
    const int nwg = nby << 2;
    int id = blockIdx.x;

    if (id >= nwg) {                 // ---------- rowdot role ----------
        int row = (id - nwg) * 4 + w;
        if (row >= rdN) return;
        short8v h = ((const short8v*)(rdH + (size_t)row * HH))[lane];
        short8v t = ((const short8v*)(rdT + (size_t)row * HH))[lane];
        const float4* up = (const float4*)rduv + lane * 2;
        const float4* vp = (const float4*)(rduv + HH) + lane * 2;
        float4 u0 = up[0], u1 = up[1], v0 = vp[0], v1 = vp[1];
        float a = bf2f(h[0])*u0.x + bf2f(h[1])*u0.y + bf2f(h[2])*u0.z + bf2f(h[3])*u0.w
                + bf2f(h[4])*u1.x + bf2f(h[5])*u1.y + bf2f(h[6])*u1.z + bf2f(h[7])*u1.w;
        float b = bf2f(t[0])*v0.x + bf2f(t[1])*v0.y + bf2f(t[2])*v0.z + bf2f(t[3])*v0.w
                + bf2f(t[4])*v1.x + bf2f(t[5])*v1.y + bf2f(t[6])*v1.z + bf2f(t[7])*v1.w;
#pragma unroll
        for (int m = 32; m >= 1; m >>= 1) {
            a += __shfl_xor(a, m);
            b += __shfl_xor(b, m);
        }
        if (lane == 0) { rdss[row] = a + rds0[0]; rdts[row] = b + rds0[1]; }
        return;
    }

    // ---------- GEMM role ----------
    const int q = nwg >> 3, r = nwg & 7;
    int xcd = id & 7, wi = id >> 3;
    int wgid = (xcd < r ? xcd * (q + 1) : r * (q + 1) + (xcd - r) * q) + wi;
    const int col0 = (wgid & 3) * 128;
    const int row0 = (wgid >> 2) * 128;

    const int wr = (w >> 1) * 64;
    const int wc = (w & 1) * 64;

    const short* gsrc[8];
#pragma unroll
    for (int g = 0; g < 8; ++g) {
        int p = w * 512 + g * 64 + lane;
        if (p < 1024) {
            int row = p >> 3;
            int c = (p & 7) ^ (row & 7);
            int ga = row0 + row; if (ga >= M) ga = M - 1;
            gsrc[g] = X + (size_t)ga * K + c * 8;
        } else {
            int qq = p - 1024;
            int col = qq >> 3;
            int c = (qq & 7) ^ (col & 7);
            gsrc[g] = WT + (size_t)(col0 + col) * K + c * 8;
        }
    }

    int ar[2][4], br[2][4];
#pragma unroll
    for (int kk = 0; kk < 2; ++kk) {
#pragma unroll
        for (int i = 0; i < 4; ++i) {
            int rr = wr + i * 16 + (lane & 15);
            ar[kk][i] = rr * 8 + ((kk * 4 + (lane >> 4)) ^ (rr & 7));
            int nn = wc + i * 16 + (lane & 15);
            br[kk][i] = 1024 + nn * 8 + ((kk * 4 + (lane >> 4)) ^ (nn & 7));
        }
    }

    f32x4 acc[4][4];
#pragma unroll
    for (int i = 0; i < 4; ++i)
#pragma unroll
        for (int j = 0; j < 4; ++j)
            acc[i][j] = (f32x4){0.f, 0.f, 0.f, 0.f};

    auto stage = [&](int buf, int kk) {
        short8v* base = pool + buf * 2048 + w * 512;
#pragma unroll
        for (int g = 0; g < 8; ++g)
            gload_lds16(gsrc[g] + kk, base + g * 64);
    };

    const int nt = K >> 6;
    stage(0, 0);
    if (nt > 1) stage(1, 64);
    int cur = 0;
    for (int t = 0; t < nt; ++t) {
        if (t + 1 < nt) asm volatile("s_waitcnt vmcnt(8)" ::: "memory");
        else            asm volatile("s_waitcnt vmcnt(0)" ::: "memory");
        __builtin_amdgcn_s_barrier();
        const short8v* S = pool + cur * 2048;
#pragma unroll
        for (int kk = 0; kk < 2; ++kk) {
            short8v af[4], bf[4];
#pragma unroll
            for (int i = 0; i < 4; ++i) af[i] = S[ar[kk][i]];
#pragma unroll
            for (int j = 0; j < 4; ++j) bf[j] = S[br[kk][j]];
#pragma unroll
            for (int i = 0; i < 4; ++i)
#pragma unroll
                for (int j = 0; j < 4; ++j)
                    acc[i][j] = __builtin_amdgcn_mfma_f32_16x16x32_bf16(af[i], bf[j], acc[i][j], 0, 0, 0);
        }
        __builtin_amdgcn_s_barrier();
        if (t + 2 < nt) stage(cur, (t + 2) * 64);
        cur ^= 1;
    }

    float bj[4];
#pragma unroll
    for (int j = 0; j < 4; ++j)
        bj[j] = bias[col0 + wc + j * 16 + (lane & 15)];

    if (outF) {
#pragma unroll
        for (int i = 0; i < 4; ++i) {
#pragma unroll
            for (int rr = 0; rr < 4; ++rr) {
                int row = row0 + wr + i * 16 + (lane >> 4) * 4 + rr;
                if (row < M) {
                    float* op = outF + (size_t)row * HH + col0 + wc + (lane & 15);
#pragma unroll
                    for (int j = 0; j < 4; ++j) op[j * 16] = acc[i][j][rr] + bj[j];
                }
            }
        }
    }
    if (outB) {   // block-cooperative bf16 epilogue, padded stride 136
        short* lt = (short*)pool;    // [128][136] bf16 = 34 KB
#pragma unroll
        for (int i = 0; i < 4; ++i)
#pragma unroll
            for (int rr = 0; rr < 4; ++rr) {
                int lrow = wr + i * 16 + (lane >> 4) * 4 + rr;
#pragma unroll
                for (int j = 0; j < 4; ++j)
                    lt[lrow * 136 + wc + j * 16 + (lane & 15)] = f2bf(acc[i][j][rr] + bj[j]);
            }
        __syncthreads();
#pragma unroll
        for (int k = 0; k < 8; ++k) {
            int row = (tid >> 4) + 16 * k;
            int seg = tid & 15;
            int grow = row0 + row;
            if (grow < M) {
                short8v vv = *(short8v*)(lt + row * 136 + seg * 8);
                *(short8v*)(outB + (size_t)grow * HH + col0 + seg * 8) = vv;
            }
        }
    }
}

// ---------------- MFMA GEMM, fp32-A variant v2 (128x128, BK=32, 2-stage) ----
// A: global fp32 -> regs (issued early) -> bf16 convert ONCE -> swizzled
// ds_write. B: global_load_lds. Counted vmcnt(6) pipeline; inner loop
// identical to the bf16 path. Dual A-source (rows < NA: XA, else XB2).
__global__ __launch_bounds__(256)
void mfma_linf(const float* __restrict__ XA, const float* __restrict__ XB2,
               int NA, const short* __restrict__ WT,
               const float* __restrict__ bias, short* __restrict__ outB,
               int M, int K)
{
    __shared__ short8v pool[2304];   // 2 stages x 1024 slots + epilogue pad = 36 KB

    const int tid = threadIdx.x;
    const int lane = tid & 63;
    const int w = tid >> 6;

    const int nby = (M + 127) >> 7;
    const int nwg = nby << 2;
    const int q = nwg >> 3, r = nwg & 7;
    int id = blockIdx.x;
    int xcd = id & 7, wi = id >> 3;
    int wgid = (xcd < r ? xcd * (q + 1) : r * (q + 1) + (xcd - r) * q) + wi;
    const int col0 = (wgid & 3) * 128;
    const int row0 = (wgid >> 2) * 128;

    const int wr = (w >> 1) * 64;
    const int wc = (w & 1) * 64;

    // A reg-staging: thread covers row srow, chunks {sc0, sc0+1} (16 fp32)
    const int srow = tid >> 1;
    const int sc0 = (tid & 1) * 2;
    int garow = row0 + srow; if (garow >= M) garow = M - 1;
    const float* abase = ((garow < NA) ? XA + (size_t)garow * K
                                       : XB2 + (size_t)(garow - NA) * K) + sc0 * 8;
    const int aswz = (srow >> 1) & 3;
    const int wi0 = srow * 4 + (sc0 ^ aswz);
    const int wi1 = srow * 4 + ((sc0 + 1) ^ aswz);

    // B staging via gload_lds (pre-swizzled source), 2 slots/thread
    const short* bsrc0; const short* bsrc1;
    int bbase0, bbase1;
    {
        int p0 = w * 128 + lane;
        int col = p0 >> 2;
        int c = (p0 & 3) ^ ((col >> 1) & 3);
        bsrc0 = WT + (size_t)(col0 + col) * K + c * 8;
        bbase0 = w * 128;
        int p1 = w * 128 + 64 + lane;
        col = p1 >> 2;
        c = (p1 & 3) ^ ((col >> 1) & 3);
        bsrc1 = WT + (size_t)(col0 + col) * K + c * 8;
        bbase1 = w * 128 + 64;
    }

    int ar[4], br[4];
#pragma unroll
    for (int i = 0; i < 4; ++i) {
        int rr = wr + i * 16 + (lane & 15);
        ar[i] = rr * 4 + ((lane >> 4) ^ ((rr >> 1) & 3));
        int nn = wc + i * 16 + (lane & 15);
        br[i] = 512 + nn * 4 + ((lane >> 4) ^ ((nn >> 1) & 3));
    }

    f32x4 acc[4][4];
#pragma unroll
    for (int i = 0; i < 4; ++i)
#pragma unroll
        for (int j = 0; j < 4; ++j)
            acc[i][j] = (f32x4){0.f, 0.f, 0.f, 0.f};

    const int nt = K >> 5;            // 16 (K=512) or 8 (K=256); always even
    float4 rA0[4], rA1[4];

#define ISSUE_A(RA, T) {                                                   \
        const float4* p_ = (const float4*)(abase + (T) * 32);              \
        RA[0] = p_[0]; RA[1] = p_[1]; RA[2] = p_[2]; RA[3] = p_[3]; }
#define ISSUE_B(BUF, T) {                                                  \
        short8v* bb_ = pool + (BUF) * 1024 + 512;                          \
        gload_lds16(bsrc0 + (T) * 32, bb_ + bbase0);                       \
        gload_lds16(bsrc1 + (T) * 32, bb_ + bbase1); }
#define LINF_BODY(BUF, RA, T) {                                            \
        short8v s0_, s1_;                                                  \
        s0_[0]=f2bf(RA[0].x); s0_[1]=f2bf(RA[0].y); s0_[2]=f2bf(RA[0].z); s0_[3]=f2bf(RA[0].w); \
        s0_[4]=f2bf(RA[1].x); s0_[5]=f2bf(RA[1].y); s0_[6]=f2bf(RA[1].z); s0_[7]=f2bf(RA[1].w); \
        s1_[0]=f2bf(RA[2].x); s1_[1]=f2bf(RA[2].y); s1_[2]=f2bf(RA[2].z); s1_[3]=f2bf(RA[2].w); \
        s1_[4]=f2bf(RA[3].x); s1_[5]=f2bf(RA[3].y); s1_[6]=f2bf(RA[3].z); s1_[7]=f2bf(RA[3].w); \
        short8v* A_ = pool + (BUF) * 1024;                                 \
        A_[wi0] = s0_; A_[wi1] = s1_;                                      \
        if ((T) + 1 < nt) asm volatile("s_waitcnt vmcnt(6) lgkmcnt(0)" ::: "memory"); \
        else              asm volatile("s_waitcnt vmcnt(0) lgkmcnt(0)" ::: "memory"); \
        __builtin_amdgcn_s_barrier();                                      \
        const short8v* S_ = pool + (BUF) * 1024;                           \
        short8v af_[4], bf_[4];                                            \
        _Pragma("unroll")                                                  \
        for (int i_ = 0; i_ < 4; ++i_) af_[i_] = S_[ar[i_]];               \
        _Pragma("unroll")                                                  \
        for (int j_ = 0; j_ < 4; ++j_) bf_[j_] = S_[br[j_]];               \
        _Pragma("unroll")                                                  \
        for (int i_ = 0; i_ < 4; ++i_)                                     \
            _Pragma("unroll")                                              \
            for (int j_ = 0; j_ < 4; ++j_)                                 \
                acc[i_][j_] = __builtin_amdgcn_mfma_f32_16x16x32_bf16(af_[i_], bf_[j_], acc[i_][j_], 0, 0, 0); \
        __builtin_amdgcn_s_barrier();                                      \
        if ((T) + 2 < nt) { ISSUE_A(RA, (T) + 2); ISSUE_B(BUF, (T) + 2); } }

    ISSUE_A(rA0, 0);
    ISSUE_B(0, 0);
    ISSUE_A(rA1, 1);
    ISSUE_B(1, 1);
    for (int t = 0; t < nt; t += 2) {
        LINF_BODY(0, rA0, t);
        LINF_BODY(1, rA1, t + 1);
    }
#undef ISSUE_A
#undef ISSUE_B
#undef LINF_BODY

    float bj[4];
#pragma unroll
    for (int j = 0; j < 4; ++j)
        bj[j] = bias[col0 + wc + j * 16 + (lane & 15)];

    // block-cooperative bf16 epilogue (padded stride 136; 34 KB <= 36 KB)
    short* lt = (short*)pool;
#pragma unroll
    for (int i = 0; i < 4; ++i)
#pragma unroll
        for (int rr = 0; rr < 4; ++rr) {
            int lrow = wr + i * 16 + (lane >> 4) * 4 + rr;
#pragma unroll
            for (int j = 0; j < 4; ++j)
                lt[lrow * 136 + wc + j * 16 + (lane & 15)] = f2bf(acc[i][j][rr] + bj[j]);
        }
    __syncthreads();
#pragma unroll
    for (int k = 0; k < 8; ++k) {
        int row = (tid >> 4) + 16 * k;
        int seg = tid & 15;
        int grow = row0 + row;
        if (grow < M) {
            short8v vv = *(short8v*)(lt + row * 136 + seg * 8);
            *(short8v*)(outB + (size_t)grow * HH + col0 + seg * 8) = vv;
        }
    }
}

// ---------------- gat_pre for BOTH relations (one launch) -------------------
__global__ __launch_bounds__(256)
void gat_pre2(const float* __restrict__ gfW, const float* __restrict__ gfb,
              const float* __restrict__ gaw, float* __restrict__ uvall,
              float* __restrict__ s0t0all)
{
    int rrel = blockIdx.y;
    const float* fW = gfW + (size_t)rrel * HH * HH;
    const float* fb = gfb + rrel * HH;
    const float* aw = gaw + (size_t)rrel * 2 * HH;
    float* uv = uvall + rrel * 1024;
    float* s0t0 = s0t0all + rrel * 4;
    int row = blockIdx.x * 4 + (threadIdx.x >> 6);
    int lane = threadIdx.x & 63;
    const float4* ah = (const float4*)aw;
    const float4* at = (const float4*)(aw + HH);
    const float4* fp;
    if (row < 512)       fp = (const float4*)(fW + (size_t)row * HH);
    else if (row == 512) fp = (const float4*)fb;
    else return;
    float du = 0.f, dv = 0.f;
#pragma unroll
    for (int l = 0; l < 2; ++l) {
        int idx = lane * 2 + l;
        float4 f = fp[idx], a = ah[idx], b = at[idx];
        du += f.x*a.x + f.y*a.y + f.z*a.z + f.w*a.w;
        dv += f.x*b.x + f.y*b.y + f.z*b.z + f.w*b.w;
    }
#pragma unroll
    for (int m = 32; m >= 1; m >>= 1) {
        du += __shfl_xor(du, m);
        dv += __shfl_xor(dv, m);
    }
    if (lane == 0) {
        if (row < 512) { uv[row] = du; uv[512 + row] = dv; }
        else           { s0t0[0] = du; s0t0[1] = dv; }
    }
}

// ---------------- CSR build ----------------
__global__ __launch_bounds__(256)
void count2_kernel(const int* __restrict__ s0, const int* __restrict__ s1,
                   int* __restrict__ c0, int* __restrict__ c1, int E)
{
    int i = blockIdx.x * blockDim.x + threadIdx.x;
    if (i < E) atomicAdd(&c0[s0[i]], 1);
    else if (i < 2 * E) atomicAdd(&c1[s1[i - E]], 1);
}

__global__ __launch_bounds__(1024)
void scan2_kernel(const int* __restrict__ c0, const int* __restrict__ c1,
                  int* __restrict__ o0, int* __restrict__ o1,
                  int* __restrict__ u0, int* __restrict__ u1, int n)
{
    const int* counts = blockIdx.x ? c1 : c0;
    int* offs = blockIdx.x ? o1 : o0;
    int* curs = blockIdx.x ? u1 : u0;
    __shared__ int part[1024];
    const int tid = threadIdx.x;
    const int CH = (n + 1023) / 1024;
    const int base = tid * CH;
    int s = 0;
    for (int i = 0; i < CH; ++i) {
        int idx = base + i;
        if (idx < n) s += counts[idx];
    }
    part[tid] = s;
    __syncthreads();
    for (int d = 1; d < 1024; d <<= 1) {
        int v = 0;
        if (tid >= d) v = part[tid - d];
        __syncthreads();
        if (tid >= d) part[tid] += v;
        __syncthreads();
    }
    int run = (tid == 0) ? 0 : part[tid - 1];
    for (int i = 0; i < CH; ++i) {
        int idx = base + i;
        if (idx < n) { offs[idx] = run; curs[idx] = run; run += counts[idx]; }
    }
    if (tid == 1023) offs[n] = run;
}

// fill CSR: target ids, edge weights, original edge index (for canonical sort)
__global__ __launch_bounds__(256)
void fill_kernel(const int* __restrict__ src, const int* __restrict__ tgt,
                 const float* __restrict__ ss, const float* __restrict__ ts,
                 const float* __restrict__ ab_ptr, int* __restrict__ cursor,
                 int* __restrict__ tvals, float* __restrict__ wv,
                 int* __restrict__ eidx, int E)
{
    int i = blockIdx.x * blockDim.x + threadIdx.x;
    if (i >= E) return;
    int s = src[i], t = tgt[i];
    int pos = atomicAdd(&cursor[s], 1);
    tvals[pos] = t;
    wv[pos] = expf(tanhf(ss[s] + ts[t] + ab_ptr[0]));
    eidx[pos] = i;
}

// ---------------- canonical bucket sort (determinism) -----------------------
__global__ __launch_bounds__(256)
void sortbkt_kernel(const int* __restrict__ offs, int* __restrict__ tvals,
                    float* __restrict__ wv, const int* __restrict__ eidx, int N)
{
    __shared__ int   lt[4][512];
    __shared__ float lw[4][512];
    int w = threadIdx.x >> 6, lane = threadIdx.x & 63;
    int s = blockIdx.x * 4 + w;
    if (s >= N) return;
    int beg = offs[s], end = offs[s + 1];
    int L = end - beg;
    if (L <= 1) return;
    if (L <= 64) {
        int e = 0x7fffffff, t = 0; float fw = 0.f;
        if (lane < L) { e = eidx[beg + lane]; t = tvals[beg + lane]; fw = wv[beg + lane]; }
        int r = 0;
        for (int k = 0; k < L; ++k) {
            int ek = __shfl(e, k);
            r += (ek < e) ? 1 : 0;
        }
        if (lane < L) { tvals[beg + r] = t; wv[beg + r] = fw; }
    } else if (L <= 512) {
        for (int j = lane; j < L; j += 64) { lt[w][j] = tvals[beg + j]; lw[w][j] = wv[beg + j]; }
        asm volatile("s_waitcnt lgkmcnt(0) vmcnt(0)" ::: "memory");
        for (int j = lane; j < L; j += 64) {
            int e = eidx[beg + j];
            int r = 0;
            for (int k = 0; k < L; ++k) r += (eidx[beg + k] < e) ? 1 : 0;
            tvals[beg + r] = lt[w][j]; wv[beg + r] = lw[w][j];
        }
    }
}

// ---------------- fused GAT aggregate + combine (bf16 rows) -----------------
// 8-wide + 4-wide + scalar gather unroll (more row loads in flight).
__global__ __launch_bounds__(256)
void gat_agg_kernel(const int* __restrict__ offs, const int* __restrict__ tvals,
                    const float* __restrict__ wv, const short* __restrict__ T,
                    const short* __restrict__ head, const float* __restrict__ gbias,
                    short* __restrict__ out, int N)
{
    int s = blockIdx.x * 4 + (threadIdx.x >> 6);
    int lane = threadIdx.x & 63;
    if (s >= N) return;
    const int beg = offs[s], end = offs[s + 1];
    float a[8];
#pragma unroll
    for (int q = 0; q < 8; ++q) a[q] = 0.f;
    float den = 0.f;

    int j = beg;
    for (; j + 8 <= end; j += 8) {
        short8v v[8];
        float wgt[8];
#pragma unroll
        for (int u = 0; u < 8; ++u) {
            wgt[u] = wv[j + u];
            v[u] = ((const short8v*)(T + (size_t)tvals[j + u] * HH))[lane];
        }
#pragma unroll
        for (int u = 0; u < 8; ++u) {
            den += wgt[u];
#pragma unroll
            for (int q = 0; q < 8; ++q) a[q] = fmaf(wgt[u], bf2f(v[u][q]), a[q]);
        }
    }
    for (; j + 4 <= end; j += 4) {
        short8v v[4];
        float wgt[4];
#pragma unroll
        for (int u = 0; u < 4; ++u) {
            wgt[u] = wv[j + u];
            v[u] = ((const short8v*)(T + (size_t)tvals[j + u] * HH))[lane];
        }
#pragma unroll
        for (int u = 0; u < 4; ++u) {
            den += wgt[u];
#pragma unroll
            for (int q = 0; q < 8; ++q) a[q] = fmaf(wgt[u], bf2f(v[u][q]), a[q]);
        }
    }
    for (; j < end; ++j) {
        int t = tvals[j];
        float w = wv[j];
        short8v tv = ((const short8v*)(T + (size_t)t * HH))[lane];
        den += w;
#pragma unroll
        for (int q = 0; q < 8; ++q) a[q] = fmaf(w, bf2f(tv[q]), a[q]);
    }
    float inv = (den > 0.f) ? 1.f / den : 0.f;

    short8v h = ((const short8v*)(head + (size_t)s * HH))[lane];
    const float4* bp = (const float4*)gbias + lane * 2;
    float4 b0 = bp[0], b1 = bp[1];
    float bb[8] = {b0.x, b0.y, b0.z, b0.w, b1.x, b1.y, b1.z, b1.w};
    short8v o;
#pragma unroll
    for (int q = 0; q < 8; ++q)
        o[q] = f2bf((bf2f(h[q]) + a[q] * inv + bb[q]) * 0.5f);
    ((short8v*)(out + (size_t)s * HH))[lane] = o;
}

// ---------------- single tanh+LN (d=0 layers) -------------------------------
__global__ __launch_bounds__(256)
void tanh_ln_kernel(const short* __restrict__ Z,
                    const float* __restrict__ g, const float* __restrict__ bta,
                    short* __restrict__ outB, int N)
{
    int row = blockIdx.x * 4 + (threadIdx.x >> 6);
    int lane = threadIdx.x & 63;
    if (row >= N) return;
    short8v zv = ((const short8v*)(Z + (size_t)row * HH))[lane];
    float v[8];
    float sum = 0.f, sum2 = 0.f;
#pragma unroll
    for (int q = 0; q < 8; ++q) {
        float t = tanhf(bf2f(zv[q]));
        v[q] = t; sum += t; sum2 = fmaf(t, t, sum2);
    }
#pragma unroll
    for (int m = 32; m >= 1; m >>= 1) {
        sum += __shfl_xor(sum, m); sum2 += __shfl_xor(sum2, m);
    }
    float mu = sum * (1.f/HH);
    float rs = rsqrtf(sum2 * (1.f/HH) - mu*mu + 1e-5f);
    const float4* gp = (const float4*)g + lane * 2;
    const float4* bp = (const float4*)bta + lane * 2;
    float4 g0 = gp[0], g1 = gp[1], c0 = bp[0], c1 = bp[1];
    float gg[8] = {g0.x, g0.y, g0.z, g0.w, g1.x, g1.y, g1.z, g1.w};
    float cc[8] = {c0.x, c0.y, c0.z, c0.w, c1.x, c1.y, c1.z, c1.w};
    short8v ob;
#pragma unroll
    for (int q = 0; q < 8; ++q) ob[q] = f2bf((v[q]-mu)*rs*gg[q] + cc[q]);
    ((short8v*)(outB + (size_t)row * HH))[lane] = ob;
}

// ---------------- fused double LN (d=1 + residual) --------------------------
__global__ __launch_bounds__(256)
void tanh_ln2_kernel(const short* __restrict__ Z, const float* __restrict__ sc,
                     const float* __restrict__ g1, const float* __restrict__ b1,
                     const float* __restrict__ g2, const float* __restrict__ b2,
                     short* __restrict__ outB, float* __restrict__ outF,
                     const float* __restrict__ cWp, const float* __restrict__ cbp,
                     float* __restrict__ outCls, int N)
{
    int row = blockIdx.x * 4 + (threadIdx.x >> 6);
    int lane = threadIdx.x & 63;
    if (row >= N) return;
    short8v zv = ((const short8v*)(Z + (size_t)row * HH))[lane];
    float v[8];
    float sum = 0.f, sum2 = 0.f;
#pragma unroll
    for (int q = 0; q < 8; ++q) {
        float t = tanhf(bf2f(zv[q]));
        v[q] = t; sum += t; sum2 = fmaf(t, t, sum2);
    }
#pragma unroll
    for (int m = 32; m >= 1; m >>= 1) {
        sum += __shfl_xor(sum, m); sum2 += __shfl_xor(sum2, m);
    }
    float mu = sum * (1.f/HH);
    float rs = rsqrtf(sum2 * (1.f/HH) - mu*mu + 1e-5f);
    {
        const float4* gp = (const float4*)g1 + lane * 2;
        const float4* bp = (const float4*)b1 + lane * 2;
        float4 g0 = gp[0], g1v = gp[1], c0 = bp[0], c1 = bp[1];
        float gg[8] = {g0.x, g0.y, g0.z, g0.w, g1v.x, g1v.y, g1v.z, g1v.w};
        float cc[8] = {c0.x, c0.y, c0.z, c0.w, c1.x, c1.y, c1.z, c1.w};
        const float4* sp = (const float4*)(sc + (size_t)row * HH) + lane * 2;
        float4 s0 = sp[0], s1 = sp[1];
        float ssv[8] = {s0.x, s0.y, s0.z, s0.w, s1.x, s1.y, s1.z, s1.w};
        sum = 0.f; sum2 = 0.f;
#pragma unroll
        for (int q = 0; q < 8; ++q) {
            float x2 = (v[q]-mu)*rs*gg[q] + cc[q];
            float t = tanhf(ssv[q] + x2);
            v[q] = t; sum += t; sum2 = fmaf(t, t, sum2);
        }
    }
#pragma unroll
    for (int m = 32; m >= 1; m >>= 1) {
        sum += __shfl_xor(sum, m); sum2 += __shfl_xor(sum2, m);
    }
    mu = sum * (1.f/HH);
    rs = rsqrtf(sum2 * (1.f/HH) - mu*mu + 1e-5f);
    const float4* gp = (const float4*)g2 + lane * 2;
    const float4* bp = (const float4*)b2 + lane * 2;
    float4 g0 = gp[0], g1v = gp[1], c0 = bp[0], c1 = bp[1];
    float gg[8] = {g0.x, g0.y, g0.z, g0.w, g1v.x, g1v.y, g1v.z, g1v.w};
    float cc[8] = {c0.x, c0.y, c0.z, c0.w, c1.x, c1.y, c1.z, c1.w};
    float o[8];
#pragma unroll
    for (int q = 0; q < 8; ++q) o[q] = (v[q]-mu)*rs*gg[q] + cc[q];
    if (outB) {
        short8v ob;
#pragma unroll
        for (int q = 0; q < 8; ++q) ob[q] = f2bf(o[q]);
        ((short8v*)(outB + (size_t)row * HH))[lane] = ob;
    }
    if (outF) {
        float4* op = (float4*)(outF + (size_t)row * HH) + lane * 2;
        op[0] = make_float4(o[0], o[1], o[2], o[3]);
        op[1] = make_float4(o[4], o[5], o[6], o[7]);
    }
    if (cWp) {
        const float4* wp = (const float4*)cWp + lane * 2;
        float4 w0 = wp[0], w1 = wp[1];
        float acc = o[0]*w0.x + o[1]*w0.y + o[2]*w0.z + o[3]*w0.w
                  + o[4]*w1.x + o[5]*w1.y + o[6]*w1.z + o[7]*w1.w;
#pragma unroll
        for (int m = 32; m >= 1; m >>= 1) acc += __shfl_xor(acc, m);
        if (lane == 0) outCls[row] = 1.f / (1.f + expf(-(acc + cbp[0])));
    }
}

extern "C" void kernel_launch(void* const* d_in, const int* in_sizes, int n_in,
                              void* d_out, int out_size, void* d_ws, size_t ws_size,
                              hipStream_t stream)
{
    (void)in_sizes; (void)n_in; (void)out_size; (void)ws_size;
    const int N = NN, E = NE, H = HH;
    const size_t NHf = (size_t)N * H;

    const float* fu0 = (const float*)d_in[0];
    const float* fi1 = (const float*)d_in[3];
    const float* fu2 = (const float*)d_in[4];
    const int* eUI0 = (const int*)d_in[6];
    const int* eIU1 = (const int*)d_in[9];
    const float* Wu  = (const float*)d_in[10];
    const float* bu  = (const float*)d_in[11];
    const float* Wi  = (const float*)d_in[12];
    const float* bi  = (const float*)d_in[13];
    const float* gfW = (const float*)d_in[14];
    const float* gfb = (const float*)d_in[15];
    const float* gaw = (const float*)d_in[16];
    const float* gab = (const float*)d_in[17];
    const float* gbias = (const float*)d_in[18];
    const float* prW = (const float*)d_in[19];
    const float* prb = (const float*)d_in[20];
    const float* dW  = (const float*)d_in[21];
    const float* db  = (const float*)d_in[22];
    const float* dlg = (const float*)d_in[23];
    const float* dlb = (const float*)d_in[24];
    const float* rlg = (const float*)d_in[25];
    const float* rlb = (const float*)d_in[26];
    const float* cW  = (const float*)d_in[27];
    const float* cb  = (const float*)d_in[28];

    // fp32 region
    float* B5     = (float*)d_ws;      // residual sc (fp32)
    float* ssb    = B5 + NHf;          // [N]
    float* tsb    = ssb + N;           // [N]
    float* uvall  = tsb + N;           // [2048]
    float* s0t0a  = uvall + 2048;      // [8]
    float* wvb    = s0t0a + 8;         // [E]
    int* counts0 = (int*)(wvb + E);
    int* counts1 = counts0 + N;
    int* offs0   = counts1 + N;
    int* offs1   = offs0 + N + 1;
    int* cur0    = offs1 + N + 1;
    int* cur1    = cur0 + N;
    int* tvals   = cur1 + N;           // [E]
    int* eidxb   = tvals + E;          // [E]
    size_t boff = (size_t)((char*)(eidxb + E) - (char*)d_ws);
    boff = (boff + 15) & ~(size_t)15;
    short* SUHU  = (short*)((char*)d_ws + boff);  // [2*NHf]: su, hu0
    short* HI    = SUHU + 2 * NHf;
    short* SINEW = HI + NHf;
    short* T4    = SINEW + NHf;
    short* SUF   = T4 + NHf;
    short* WTu   = SUF + NHf;
    short* WTi   = WTu + 512 * 512;
    short* WTg0  = WTi + 512 * 256;
    short* WTg1  = WTg0 + 512 * 512;
    short* WTpr  = WTg1 + 512 * 512;
    short* WTd   = WTpr + 512 * 512;
    short* SU  = SUHU;
    short* HU0 = SUHU + NHf;
    short* XB  = SINEW;
    short* ZB  = SU;

    // ---- batched pre-passes ----
    hipLaunchKernelGGL(wtr_all, dim3(16, 16, 9), dim3(32, 8), 0, stream,
                       Wu, Wi, gfW, prW, dW, WTu, WTi, WTg0, WTg1, WTpr, WTd);
    hipMemsetAsync(counts0, 0, 2 * N * sizeof(int), stream);
    hipLaunchKernelGGL(count2_kernel, dim3((2 * E + 255) / 256), dim3(256), 0, stream,
                       eUI0, eIU1, counts0, counts1, E);
    hipLaunchKernelGGL(scan2_kernel, dim3(2), dim3(1024), 0, stream,
                       counts0, counts1, offs0, offs1, cur0, cur1, N);
    hipLaunchKernelGGL(gat_pre2, dim3(130, 2), dim3(256), 0, stream,
                       gfW, gfb, gaw, uvall, s0t0a);

    const int rgrid = (N + 3) / 4;
    const int egrid = (E + 255) / 256;
    auto MLIN = [&](const short* X, const short* WT, const float* b,
                    float* oF, short* oB, int M, int K,
                    const short* rdH, const short* rdT, const float* rduv,
                    const float* rds0) {
        int nwg = ((M + 127) / 128) * 4;
        int grid = nwg + (rdH ? rgrid : 0);
        hipLaunchKernelGGL(mfma_lin, dim3(grid), dim3(256), 0, stream,
                           X, WT, b, oF, oB, M, K,
                           rdH, rdT, rduv, rds0, ssb, tsb, N);
    };
    auto MLINF = [&](const float* XA, const float* XB2, int NA, const short* WT,
                     const float* b, short* oB, int M, int K) {
        int nwg = ((M + 127) / 128) * 4;
        hipLaunchKernelGGL(mfma_linf, dim3(nwg), dim3(256), 0, stream,
                           XA, XB2, NA, WT, b, oB, M, K);
    };

    auto GAT = [&](int r, const short* headB, const short* tailB, const short* WTg,
                   const int* edges, int* offs, int* curs, short* outB) {
        MLIN(tailB, WTg, gfb + r * H, nullptr, T4, N, 512,
             headB, tailB, uvall + r * 1024, s0t0a + r * 4);
        hipLaunchKernelGGL(fill_kernel, dim3(egrid), dim3(256), 0, stream,
                           edges, edges + E, ssb, tsb, gab + r, curs, tvals, wvb,
                           eidxb, E);
        hipLaunchKernelGGL(sortbkt_kernel, dim3(rgrid), dim3(256), 0, stream,
                           offs, tvals, wvb, eidxb, N);
        hipLaunchKernelGGL(gat_agg_kernel, dim3(rgrid), dim3(256), 0, stream,
                           offs, tvals, wvb, T4, headB, gbias + (size_t)r * H, outB, N);
    };

    // input transforms: fp32-A GEMMs read raw features directly
    MLINF(fu2, fu0, N, WTu, bu, SUHU, 2 * N, 512);    // su + hu0
    MLINF(fi1, fi1, N, WTi, bi, HI, N, 256);          // hi
    GAT(1, HI, SU, WTg1, eIU1, offs1, cur1, SINEW);
    GAT(0, HU0, SINEW, WTg0, eUI0, offs0, cur0, SUF);

    // Res_DNN head
    MLIN(SUF, WTpr, prb, B5, XB, N, 512, nullptr, nullptr, nullptr, nullptr);
    for (int r = 0; r < 2; ++r) {
        MLIN(XB, WTd + (size_t)(r * 2) * 512 * 512, db + (r * 2) * H,
             nullptr, ZB, N, 512, nullptr, nullptr, nullptr, nullptr);
        hipLaunchKernelGGL(tanh_ln_kernel, dim3(rgrid), dim3(256), 0, stream,
                           ZB, dlg + (r * 2) * H, dlb + (r * 2) * H, XB, N);
        MLIN(XB, WTd + (size_t)(r * 2 + 1) * 512 * 512, db + (r * 2 + 1) * H,
             nullptr, ZB, N, 512, nullptr, nullptr, nullptr, nullptr);
        if (r == 0) {
            hipLaunchKernelGGL(tanh_ln2_kernel, dim3(rgrid), dim3(256), 0, stream,
                               ZB, B5, dlg + H, dlb + H, rlg, rlb,
                               XB, B5, (const float*)nullptr, (const float*)nullptr,
                               (float*)nullptr, N);
        } else {
            hipLaunchKernelGGL(tanh_ln2_kernel, dim3(rgrid), dim3(256), 0, stream,
                               ZB, B5, dlg + 3 * H, dlb + 3 * H, rlg + H, rlb + H,
                               (short*)nullptr, (float*)nullptr, cW, cb,
                               (float*)d_out, N);
        }
    }
}